// Round 5
// baseline (3500.895 us; speedup 1.0000x reference)
//
#include <hip/hip_runtime.h>
#include <cstdint>
#include <cstddef>

#define WG 256
#define NB 16  // batch

// Layout "L": arr[(n*16 + b)*F + f]  — node-major, batch, feature.
// A node's row is 16*F contiguous floats (2KB at F=32, 4KB at F=64).

// ---------------- small utility kernels ----------------

__global__ void k_zero_i(int* __restrict__ p, int n) {
  int i = blockIdx.x * WG + threadIdx.x;
  if (i < n) p[i] = 0;
}

__global__ void k_hist(const int* __restrict__ edges, int E,
                       int* __restrict__ dsrc, int* __restrict__ dtgt) {
  int e = blockIdx.x * WG + threadIdx.x;
  if (e >= E) return;
  atomicAdd(&dsrc[edges[e]], 1);
  atomicAdd(&dtgt[edges[E + e]], 1);
}

__global__ void k_scan(const int* __restrict__ deg, int N,
                       int* __restrict__ rowptr, int* __restrict__ cursor) {
  __shared__ int s[WG];
  int t = threadIdx.x;
  int chunk = (N + WG - 1) / WG;
  int a = t * chunk;
  int b = min(N, a + chunk);
  int sum = 0;
  for (int i = a; i < b; i++) sum += deg[i];
  s[t] = sum;
  __syncthreads();
  for (int off = 1; off < WG; off <<= 1) {
    int v = (t >= off) ? s[t - off] : 0;
    __syncthreads();
    s[t] += v;
    __syncthreads();
  }
  int run = (t == 0) ? 0 : s[t - 1];
  for (int i = a; i < b; i++) {
    rowptr[i] = run;
    cursor[i] = run;
    run += deg[i];
  }
  if (t == 0) rowptr[N] = s[WG - 1];
}

__global__ void k_fill(const int* __restrict__ edges, int E,
                       const int* __restrict__ dsrc, int* __restrict__ cursor,
                       int* __restrict__ csrc, float* __restrict__ csw) {
  int e = blockIdx.x * WG + threadIdx.x;
  if (e >= E) return;
  int s = edges[e], t = edges[E + e];
  float da = (float)dsrc[s], db = (float)dsrc[t];
  float wa = (da > 0.f) ? (1.0f / sqrtf(da)) : 0.f;
  float wb = (db > 0.f) ? (1.0f / sqrtf(db)) : 0.f;
  int pos = atomicAdd(&cursor[t], 1);
  csrc[pos] = s;
  csw[pos] = wa * wb;
}

// transpose x (b,n,f3) -> L layout (n,b,f3)
__global__ void k_tr_x(const float* __restrict__ x, float* __restrict__ out) {
  int i = blockIdx.x * WG + threadIdx.x;
  if (i >= NB * 20000 * 3) return;
  int f = i % 3;
  int b = (i / 3) % NB;
  int n = i / 48;
  out[i] = x[((size_t)b * 20000 + n) * 3 + f];
}

// ---------------- threefry eps (verified vs harness JAX ref) ----------------

static __device__ __forceinline__ float erfinv_f(float x) {
  float w = -log1pf(-x * x);
  float p;
  if (w < 5.0f) {
    w -= 2.5f;
    p = 2.81022636e-08f;
    p = fmaf(p, w, 3.43273939e-07f);
    p = fmaf(p, w, -3.5233877e-06f);
    p = fmaf(p, w, -4.39150654e-06f);
    p = fmaf(p, w, 0.00021858087f);
    p = fmaf(p, w, -0.00125372503f);
    p = fmaf(p, w, -0.00417768164f);
    p = fmaf(p, w, 0.246640727f);
    p = fmaf(p, w, 1.50140941f);
  } else {
    w = sqrtf(w) - 3.0f;
    p = -0.000200214257f;
    p = fmaf(p, w, 0.000100950558f);
    p = fmaf(p, w, 0.00134934322f);
    p = fmaf(p, w, -0.00367342844f);
    p = fmaf(p, w, 0.00573950773f);
    p = fmaf(p, w, -0.0076224613f);
    p = fmaf(p, w, 0.00943887047f);
    p = fmaf(p, w, 1.00167406f);
    p = fmaf(p, w, 2.83297682f);
  }
  return p * x;
}

static __device__ __forceinline__ float bits_to_normal(unsigned b) {
  float f = __uint_as_float((b >> 9) | 0x3f800000u) - 1.0f;
  const float lo = -0.99999994f;
  float u = f * (1.0f - lo) + lo;
  u = fmaxf(u, lo);
  return 1.41421356f * erfinv_f(u);
}

__global__ void k_eps(float* __restrict__ eps) {
  int i = blockIdx.x * WG + threadIdx.x;
  if (i >= 1024) return;
  unsigned x0 = 0u, x1 = (unsigned)i;
  unsigned ks[3] = {0u, 42u, 0u ^ 42u ^ 0x1BD11BDAu};
  x0 += ks[0];
  x1 += ks[1];
  const int R[2][4] = {{13, 15, 26, 6}, {17, 29, 16, 24}};
#pragma unroll
  for (int it = 0; it < 5; it++) {
#pragma unroll
    for (int j = 0; j < 4; j++) {
      x0 += x1;
      int r = R[it & 1][j];
      x1 = (x1 << r) | (x1 >> (32 - r));
      x1 ^= x0;
    }
    x0 += ks[(it + 1) % 3];
    x1 += ks[(it + 2) % 3] + (unsigned)(it + 1);
  }
  eps[i] = bits_to_normal(x0 ^ x1);
}

// ---------------- wave-per-node Chebyshev propagation ----------------
// out_row(n) = scale * sum_j w_j * in_row(src_j)  - sub_row(n)
// One 64-lane wave per node; lane c owns float4 positions {c, c+64, ...} of
// the 16*F row. Edge loop is wave-uniform (no divergence), indices broadcast.

template <int F>
__global__ __launch_bounds__(WG) void k_propw(const float* __restrict__ in,
                                              float* __restrict__ out,
                                              const float* __restrict__ sub, float scale,
                                              const int* __restrict__ rowptr,
                                              const int* __restrict__ csrc,
                                              const float* __restrict__ csw, int N) {
  constexpr int C4 = F / 16;  // float4s per lane (2 for F=32, 4 for F=64)
  int node = blockIdx.x * 4 + (threadIdx.x >> 6);
  if (node >= N) return;
  int lane = threadIdx.x & 63;
  const float4* in4 = (const float4*)in;
  float4 acc[C4];
#pragma unroll
  for (int u = 0; u < C4; u++) acc[u] = make_float4(0.f, 0.f, 0.f, 0.f);
  int beg = rowptr[node], end = rowptr[node + 1];
  int j = beg;
  for (; j + 1 < end; j += 2) {
    int s0 = __builtin_amdgcn_readfirstlane(csrc[j]);
    int s1 = __builtin_amdgcn_readfirstlane(csrc[j + 1]);
    float w0 = __int_as_float(__builtin_amdgcn_readfirstlane(__float_as_int(csw[j])));
    float w1 = __int_as_float(__builtin_amdgcn_readfirstlane(__float_as_int(csw[j + 1])));
    const float4* r0 = in4 + (size_t)s0 * (4 * F) + lane;
    const float4* r1 = in4 + (size_t)s1 * (4 * F) + lane;
#pragma unroll
    for (int u = 0; u < C4; u++) {
      float4 v0 = r0[u * 64];
      float4 v1 = r1[u * 64];
      acc[u].x = fmaf(w0, v0.x, acc[u].x); acc[u].y = fmaf(w0, v0.y, acc[u].y);
      acc[u].z = fmaf(w0, v0.z, acc[u].z); acc[u].w = fmaf(w0, v0.w, acc[u].w);
      acc[u].x = fmaf(w1, v1.x, acc[u].x); acc[u].y = fmaf(w1, v1.y, acc[u].y);
      acc[u].z = fmaf(w1, v1.z, acc[u].z); acc[u].w = fmaf(w1, v1.w, acc[u].w);
    }
  }
  if (j < end) {
    int s0 = __builtin_amdgcn_readfirstlane(csrc[j]);
    float w0 = __int_as_float(__builtin_amdgcn_readfirstlane(__float_as_int(csw[j])));
    const float4* r0 = in4 + (size_t)s0 * (4 * F) + lane;
#pragma unroll
    for (int u = 0; u < C4; u++) {
      float4 v0 = r0[u * 64];
      acc[u].x = fmaf(w0, v0.x, acc[u].x); acc[u].y = fmaf(w0, v0.y, acc[u].y);
      acc[u].z = fmaf(w0, v0.z, acc[u].z); acc[u].w = fmaf(w0, v0.w, acc[u].w);
    }
  }
  float4* o4 = (float4*)out + (size_t)node * (4 * F) + lane;
  if (sub) {
    const float4* s4 = (const float4*)sub + (size_t)node * (4 * F) + lane;
#pragma unroll
    for (int u = 0; u < C4; u++) {
      float4 sv = s4[u * 64];
      float4 r;
      r.x = fmaf(scale, acc[u].x, -sv.x); r.y = fmaf(scale, acc[u].y, -sv.y);
      r.z = fmaf(scale, acc[u].z, -sv.z); r.w = fmaf(scale, acc[u].w, -sv.w);
      o4[u * 64] = r;
    }
  } else {
#pragma unroll
    for (int u = 0; u < C4; u++) {
      float4 r;
      r.x = scale * acc[u].x; r.y = scale * acc[u].y;
      r.z = scale * acc[u].z; r.w = scale * acc[u].w;
      o4[u * 64] = r;
    }
  }
}

// F=3 variant: row = 48 floats; lanes 0..47 each own one float.
__global__ __launch_bounds__(WG) void k_propw3(const float* __restrict__ in,
                                               float* __restrict__ out,
                                               const float* __restrict__ sub, float scale,
                                               const int* __restrict__ rowptr,
                                               const int* __restrict__ csrc,
                                               const float* __restrict__ csw, int N) {
  int node = blockIdx.x * 4 + (threadIdx.x >> 6);
  if (node >= N) return;
  int lane = threadIdx.x & 63;
  if (lane >= 48) return;
  float acc = 0.f;
  int beg = rowptr[node], end = rowptr[node + 1];
  for (int j = beg; j < end; j++) {
    int s = __builtin_amdgcn_readfirstlane(csrc[j]);
    float w = __int_as_float(__builtin_amdgcn_readfirstlane(__float_as_int(csw[j])));
    acc = fmaf(w, in[(size_t)s * 48 + lane], acc);
  }
  float r = scale * acc;
  if (sub) r -= sub[(size_t)node * 48 + lane];
  out[(size_t)node * 48 + lane] = r;
}

// ---------------- fused 3-term GEMM ----------------
// out(row,g) (+)= sum_{kk<3} txs[kk](row,:) @ W[kk]; rows = N*16 in L layout.
struct Ptr3 {
  const float* p[3];
};

template <int F, int G>
__global__ __launch_bounds__(WG) void k_gemm3(Ptr3 txs, const float* __restrict__ W,
                                              const float* __restrict__ bias,
                                              float* __restrict__ out, int rows,
                                              int accum, int relu) {
  __shared__ float sW[3 * F * G];
  for (int i = threadIdx.x; i < 3 * F * G; i += WG) sW[i] = W[i];
  __syncthreads();
  int row = blockIdx.x * WG + threadIdx.x;
  if (row >= rows) return;
  float acc[G];
  float* o = out + (size_t)row * G;
  if (accum) {
    if constexpr ((G & 3) == 0) {
#pragma unroll
      for (int g = 0; g < G; g += 4) {
        float4 v = *(const float4*)(o + g);
        acc[g] = v.x; acc[g + 1] = v.y; acc[g + 2] = v.z; acc[g + 3] = v.w;
      }
    } else {
#pragma unroll
      for (int g = 0; g < G; g++) acc[g] = o[g];
    }
  } else if (bias) {
#pragma unroll
    for (int g = 0; g < G; g++) acc[g] = bias[g];
  } else {
#pragma unroll
    for (int g = 0; g < G; g++) acc[g] = 0.f;
  }
#pragma unroll
  for (int kk = 0; kk < 3; kk++) {
    const float* t = txs.p[kk] + (size_t)row * F;
    float x[F];
    if constexpr ((F & 3) == 0) {
#pragma unroll
      for (int f = 0; f < F; f += 4) {
        float4 v = *(const float4*)(t + f);
        x[f] = v.x; x[f + 1] = v.y; x[f + 2] = v.z; x[f + 3] = v.w;
      }
    } else {
#pragma unroll
      for (int f = 0; f < F; f++) x[f] = t[f];
    }
    const float* w = sW + kk * F * G;
#pragma unroll
    for (int f = 0; f < F; f++) {
      float xf = x[f];
#pragma unroll
      for (int g = 0; g < G; g++) acc[g] = fmaf(xf, w[f * G + g], acc[g]);
    }
  }
  if (relu) {
#pragma unroll
    for (int g = 0; g < G; g++) acc[g] = fmaxf(acc[g], 0.f);
  }
  if constexpr ((G & 3) == 0) {
#pragma unroll
    for (int g = 0; g < G; g += 4) {
      float4 v;
      v.x = acc[g]; v.y = acc[g + 1]; v.z = acc[g + 2]; v.w = acc[g + 3];
      *(float4*)(o + g) = v;
    }
  } else {
#pragma unroll
    for (int g = 0; g < G; g++) o[g] = acc[g];
  }
}

// ---- final level-4 cheb shortcut (L layout in, (b,n,f) out) ----
__global__ __launch_bounds__(WG) void k_final_short(const float* __restrict__ in,
                                                    const float* __restrict__ W,  // 6x32x3
                                                    float* __restrict__ out) {
  __shared__ float sW[96];
  if (threadIdx.x < 96)
    sW[threadIdx.x] = W[threadIdx.x] - W[192 + threadIdx.x] + W[384 + threadIdx.x];
  __syncthreads();
  int tid = blockIdx.x * WG + threadIdx.x;
  if (tid >= NB * 20000) return;
  int b = tid / 20000, n = tid % 20000;
  const float* t = in + ((size_t)n * 16 + b) * 32;
  float a0 = 0.f, a1 = 0.f, a2 = 0.f;
#pragma unroll
  for (int f = 0; f < 32; f += 4) {
    float4 v = *(const float4*)(t + f);
    a0 = fmaf(v.x, sW[(f + 0) * 3 + 0], a0); a1 = fmaf(v.x, sW[(f + 0) * 3 + 1], a1); a2 = fmaf(v.x, sW[(f + 0) * 3 + 2], a2);
    a0 = fmaf(v.y, sW[(f + 1) * 3 + 0], a0); a1 = fmaf(v.y, sW[(f + 1) * 3 + 1], a1); a2 = fmaf(v.y, sW[(f + 1) * 3 + 2], a2);
    a0 = fmaf(v.z, sW[(f + 2) * 3 + 0], a0); a1 = fmaf(v.z, sW[(f + 2) * 3 + 1], a1); a2 = fmaf(v.z, sW[(f + 2) * 3 + 2], a2);
    a0 = fmaf(v.w, sW[(f + 3) * 3 + 0], a0); a1 = fmaf(v.w, sW[(f + 3) * 3 + 1], a1); a2 = fmaf(v.w, sW[(f + 3) * 3 + 2], a2);
  }
  float* o = out + (size_t)tid * 3;
  o[0] = a0; o[1] = a1; o[2] = a2;
}

// exact K=6 fixup for the 79 real nodes; in is L layout. one block per batch.
__global__ __launch_bounds__(256) void k_final_fix(const float* __restrict__ in,
                                                   const float* __restrict__ W,  // 6x32x3
                                                   const int* __restrict__ rowptr,
                                                   const int* __restrict__ csrc,
                                                   const float* __restrict__ csw,
                                                   float* __restrict__ out) {
  __shared__ float B0[79 * 32], B1[79 * 32], B2[79 * 32];
  __shared__ float sacc[79 * 3];
  __shared__ float sW[576];
  int b = blockIdx.x, t = threadIdx.x;
  for (int i = t; i < 576; i += 256) sW[i] = W[i];
  for (int i = t; i < 2528; i += 256) {
    int r = i >> 5, f = i & 31;
    B0[i] = in[((size_t)r * 16 + b) * 32 + f];
  }
  __syncthreads();
  for (int i = t; i < 237; i += 256) {
    int r = i / 3, g = i % 3;
    float a = 0.f;
    for (int f = 0; f < 32; f++) a = fmaf(B0[r * 32 + f], sW[f * 3 + g], a);
    sacc[i] = a;
  }
  for (int i = t; i < 2528; i += 256) {
    int r = i >> 5, f = i & 31;
    float a = 0.f;
    for (int j = rowptr[r]; j < rowptr[r + 1]; j++) a = fmaf(csw[j], B0[csrc[j] * 32 + f], a);
    B1[i] = a;
  }
  __syncthreads();
  for (int i = t; i < 237; i += 256) {
    int r = i / 3, g = i % 3;
    float a = sacc[i];
    for (int f = 0; f < 32; f++) a = fmaf(B1[r * 32 + f], sW[96 + f * 3 + g], a);
    sacc[i] = a;
  }
  for (int i = t; i < 2528; i += 256) {
    int r = i >> 5, f = i & 31;
    float a = 0.f;
    for (int j = rowptr[r]; j < rowptr[r + 1]; j++) a = fmaf(csw[j], B1[csrc[j] * 32 + f], a);
    B2[i] = 2.f * a - B0[i];
  }
  __syncthreads();
  for (int i = t; i < 237; i += 256) {
    int r = i / 3, g = i % 3;
    float a = sacc[i];
    for (int f = 0; f < 32; f++) a = fmaf(B2[r * 32 + f], sW[192 + f * 3 + g], a);
    sacc[i] = a;
  }
  __syncthreads();
  for (int i = t; i < 2528; i += 256) {
    int r = i >> 5, f = i & 31;
    float a = 0.f;
    for (int j = rowptr[r]; j < rowptr[r + 1]; j++) a = fmaf(csw[j], B2[csrc[j] * 32 + f], a);
    B0[i] = 2.f * a - B1[i];
  }
  __syncthreads();
  for (int i = t; i < 237; i += 256) {
    int r = i / 3, g = i % 3;
    float a = sacc[i];
    for (int f = 0; f < 32; f++) a = fmaf(B0[r * 32 + f], sW[288 + f * 3 + g], a);
    sacc[i] = a;
  }
  __syncthreads();
  for (int i = t; i < 2528; i += 256) {
    int r = i >> 5, f = i & 31;
    float a = 0.f;
    for (int j = rowptr[r]; j < rowptr[r + 1]; j++) a = fmaf(csw[j], B0[csrc[j] * 32 + f], a);
    B1[i] = 2.f * a - B2[i];
  }
  __syncthreads();
  for (int i = t; i < 237; i += 256) {
    int r = i / 3, g = i % 3;
    float a = sacc[i];
    for (int f = 0; f < 32; f++) a = fmaf(B1[r * 32 + f], sW[384 + f * 3 + g], a);
    sacc[i] = a;
  }
  __syncthreads();
  for (int i = t; i < 2528; i += 256) {
    int r = i >> 5, f = i & 31;
    float a = 0.f;
    for (int j = rowptr[r]; j < rowptr[r + 1]; j++) a = fmaf(csw[j], B1[csrc[j] * 32 + f], a);
    B2[i] = 2.f * a - B0[i];
  }
  __syncthreads();
  for (int i = t; i < 237; i += 256) {
    int r = i / 3, g = i % 3;
    float a = sacc[i];
    for (int f = 0; f < 32; f++) a = fmaf(B2[r * 32 + f], sW[480 + f * 3 + g], a);
    out[((size_t)b * 20000 + r) * 3 + g] = a;
  }
}

// downsample in L layout: out row j <- relu(in row idx[j])
template <int F>
__global__ __launch_bounds__(WG) void k_ds(const float* __restrict__ in,
                                           float* __restrict__ out,
                                           const int* __restrict__ idx, int Nout) {
  int i = blockIdx.x * WG + threadIdx.x;
  int total = Nout * NB * F;
  if (i >= total) return;
  int pos = i % (NB * F);
  int j = i / (NB * F);
  float v = in[(size_t)idx[j] * NB * F + pos];
  out[i] = fmaxf(v, 0.f);
}

// upsample in L layout (relu fused on input)
template <int F>
__global__ __launch_bounds__(WG) void k_us(const float* __restrict__ in,
                                           float* __restrict__ out,
                                           const int* __restrict__ uidx,
                                           const float* __restrict__ uw, int Nf) {
  int i = blockIdx.x * WG + threadIdx.x;
  int total = Nf * NB * F;
  if (i >= total) return;
  int pos = i % (NB * F);
  int r = i / (NB * F);
  float acc = 0.f;
#pragma unroll
  for (int k = 0; k < 3; k++) {
    float v = in[(size_t)uidx[r * 3 + k] * NB * F + pos];
    acc = fmaf(uw[r * 3 + k], fmaxf(v, 0.f), acc);
  }
  out[i] = acc;
}

// ---------------- latent kernels (L layout h: (79,16,64)) ----------------

__global__ __launch_bounds__(64) void k_latent(const float* __restrict__ h,
                                               const float* __restrict__ muW,
                                               const float* __restrict__ muB,
                                               const float* __restrict__ lvW,
                                               const float* __restrict__ lvB,
                                               const float* __restrict__ eps,
                                               const float* __restrict__ label,
                                               float* __restrict__ mu_out,
                                               float* __restrict__ lv_out,
                                               float* __restrict__ hcat) {
  int b = blockIdx.x / 64;
  int g = blockIdx.x % 64;
  int l = threadIdx.x;
  float am = 0.f, al = 0.f;
  for (int i = l; i < 5056; i += 64) {
    int n = i >> 6, f = i & 63;
    float hv = h[(size_t)(n * 16 + b) * 64 + f];
    am = fmaf(hv, muW[(size_t)i * 64 + g], am);
    al = fmaf(hv, lvW[(size_t)i * 64 + g], al);
  }
  for (int off = 32; off > 0; off >>= 1) {
    am += __shfl_down(am, off, 64);
    al += __shfl_down(al, off, 64);
  }
  if (l == 0) {
    am += muB[g];
    al += lvB[g];
    mu_out[b * 64 + g] = am;
    lv_out[b * 64 + g] = al;
    hcat[b * 66 + g] = fmaf(eps[b * 64 + g], expf(0.5f * al), am);
    if (g < 2) hcat[b * 66 + 64 + g] = label[b * 2 + g];
  }
}

// writes dec_lin output directly in L layout (79,16,64)
__global__ __launch_bounds__(WG) void k_declin(const float* __restrict__ hcat,
                                               const float* __restrict__ W,
                                               const float* __restrict__ bias,
                                               float* __restrict__ out) {
  int idx = blockIdx.x * WG + threadIdx.x;
  if (idx >= NB * 5056) return;
  int b = idx / 5056, j = idx % 5056;
  int n = j >> 6, f = j & 63;
  float acc = bias[j];
  const float* hc = hcat + b * 66;
#pragma unroll
  for (int i = 0; i < 66; i++) acc = fmaf(hc[i], W[(size_t)i * 5056 + j], acc);
  out[(size_t)(n * 16 + b) * 64 + f] = fmaxf(acc, 0.f);
}

// ---------------- host orchestration ----------------

static inline dim3 grid1(long n) { return dim3((unsigned)((n + WG - 1) / WG)); }

// Cheb layer, fused: 4 buffers (in is clobbered as T3 after first gemm3).
//   T1->A, T2->B, gemm3(T0,T1,T2)->out(init)
//   T3->in, T4->A, T5->B, gemm3(T3,T4,T5)->out(accum,relu)
template <int F, int G>
static void run_cheb(float* in, float* out, float* A, float* B,
                     const float* W, const float* bias, int N, int relu_last,
                     const int* rowptr, const int* csrc, const float* csw,
                     hipStream_t st) {
  int rows = NB * N;
  dim3 gG = grid1(rows);
  dim3 gP((unsigned)((N + 3) / 4));
  if constexpr (F == 3) {
    k_propw3<<<gP, WG, 0, st>>>(in, A, nullptr, 1.f, rowptr, csrc, csw, N);
    k_propw3<<<gP, WG, 0, st>>>(A, B, in, 2.f, rowptr, csrc, csw, N);
    Ptr3 p1{{in, A, B}};
    k_gemm3<F, G><<<gG, WG, 0, st>>>(p1, W, bias, out, rows, 0, 0);
    k_propw3<<<gP, WG, 0, st>>>(B, in, A, 2.f, rowptr, csrc, csw, N);
    k_propw3<<<gP, WG, 0, st>>>(in, A, B, 2.f, rowptr, csrc, csw, N);
    k_propw3<<<gP, WG, 0, st>>>(A, B, in, 2.f, rowptr, csrc, csw, N);
    Ptr3 p2{{in, A, B}};
    k_gemm3<F, G><<<gG, WG, 0, st>>>(p2, W + 3 * F * G, nullptr, out, rows, 1, relu_last);
  } else {
    k_propw<F><<<gP, WG, 0, st>>>(in, A, nullptr, 1.f, rowptr, csrc, csw, N);
    k_propw<F><<<gP, WG, 0, st>>>(A, B, in, 2.f, rowptr, csrc, csw, N);
    Ptr3 p1{{in, A, B}};
    k_gemm3<F, G><<<gG, WG, 0, st>>>(p1, W, bias, out, rows, 0, 0);
    k_propw<F><<<gP, WG, 0, st>>>(B, in, A, 2.f, rowptr, csrc, csw, N);   // T3
    k_propw<F><<<gP, WG, 0, st>>>(in, A, B, 2.f, rowptr, csrc, csw, N);   // T4
    k_propw<F><<<gP, WG, 0, st>>>(A, B, in, 2.f, rowptr, csrc, csw, N);   // T5
    Ptr3 p2{{in, A, B}};
    k_gemm3<F, G><<<gG, WG, 0, st>>>(p2, W + 3 * F * G, nullptr, out, rows, 1, relu_last);
  }
}

extern "C" void kernel_launch(void* const* d_in, const int* in_sizes, int n_in,
                              void* d_out, int out_size, void* d_ws, size_t ws_size,
                              hipStream_t stream) {
  static const int NN[5] = {20000, 5000, 1250, 313, 79};
  static const int EE[5] = {120000, 30000, 7500, 1878, 474};
  static const int NCSR[5] = {20000, 5000, 1250, 313, 20000};

  const float* x = (const float*)d_in[0];
  const float* label = (const float*)d_in[1];
  const int* edges[5];
  for (int l = 0; l < 5; l++) edges[l] = (const int*)d_in[2 + l];
  const int* ds_idx[4];
  const int* us_idx[4];
  const float* us_w[4];
  for (int i = 0; i < 4; i++) {
    ds_idx[i] = (const int*)d_in[7 + 3 * i];
    us_idx[i] = (const int*)d_in[8 + 3 * i];
    us_w[i] = (const float*)d_in[9 + 3 * i];
  }
  const float* enc_w[4];
  const float* enc_b[4];
  for (int i = 0; i < 4; i++) {
    enc_w[i] = (const float*)d_in[19 + 2 * i];
    enc_b[i] = (const float*)d_in[20 + 2 * i];
  }
  const float* dec_w[5];
  for (int i = 0; i < 5; i++) dec_w[i] = (const float*)d_in[27 + i];
  const float* dec_b[4];
  for (int i = 0; i < 4; i++) dec_b[i] = (const float*)d_in[32 + i];
  const float* mu_w = (const float*)d_in[36];
  const float* mu_b = (const float*)d_in[37];
  const float* lv_w = (const float*)d_in[38];
  const float* lv_b = (const float*)d_in[39];
  const float* dl_w = (const float*)d_in[40];
  const float* dl_b = (const float*)d_in[41];

  float* wsf = (float*)d_ws;
  size_t off = 0;
  auto carve = [&](size_t n) -> float* {
    float* p = wsf + off;
    off += (n + 63) & ~(size_t)63;
    return p;
  };
  const size_t SLOT = 10240000;  // 16*20000*32 floats
  float* s0 = carve(SLOT);
  float* s1 = carve(SLOT);
  float* s2 = carve(SLOT);
  float* s3 = carve(SLOT);
  float* sxl = carve(960000);  // x in L layout (20000,16,3)
  int* deg_all = (int*)carve(26642 + 46563);
  int* deg_src_all = deg_all;
  int* deg_tgt_all = deg_all + 26642;
  int* rowptr_all = (int*)carve(46568);
  int* cursor_all = (int*)carve(46563);
  int* csrc_all = (int*)carve(159852);
  float* csw_all = carve(159852);
  float* eps = carve(1024);
  float* hcat = carve(1056);

  int NOFF[5], COFF[5], ROFF[5], EOFF[5];
  {
    int na = 0, ca = 0, ra = 0, ea = 0;
    for (int l = 0; l < 5; l++) {
      NOFF[l] = na; na += NN[l];
      COFF[l] = ca; ca += NCSR[l];
      ROFF[l] = ra; ra += NCSR[l] + 1;
      EOFF[l] = ea; ea += EE[l];
    }
  }

  // ---- norms + CSR build ----
  k_zero_i<<<grid1(26642 + 46563), WG, 0, stream>>>(deg_all, 26642 + 46563);
  for (int l = 0; l < 5; l++)
    k_hist<<<grid1(EE[l]), WG, 0, stream>>>(edges[l], EE[l], deg_src_all + NOFF[l],
                                            deg_tgt_all + COFF[l]);
  for (int l = 0; l < 5; l++)
    k_scan<<<1, WG, 0, stream>>>(deg_tgt_all + COFF[l], NCSR[l], rowptr_all + ROFF[l],
                                 cursor_all + COFF[l]);
  for (int l = 0; l < 5; l++)
    k_fill<<<grid1(EE[l]), WG, 0, stream>>>(edges[l], EE[l], deg_src_all + NOFF[l],
                                            cursor_all + COFF[l], csrc_all + EOFF[l],
                                            csw_all + EOFF[l]);
  k_eps<<<4, WG, 0, stream>>>(eps);
  k_tr_x<<<grid1(960000), WG, 0, stream>>>(x, sxl);

  auto RP = [&](int l) { return rowptr_all + ROFF[l]; };
  auto CS = [&](int l) { return csrc_all + EOFF[l]; };
  auto CW = [&](int l) { return csw_all + EOFF[l]; };

  float* mu_out = (float*)d_out + 960000;
  float* lv_out = (float*)d_out + 961024;

  // ---- encoder ----
  run_cheb<3, 32>(sxl, s0, s2, s3, enc_w[0], enc_b[0], 20000, 0, RP(0), CS(0), CW(0), stream);
  k_ds<32><<<grid1((long)5000 * NB * 32), WG, 0, stream>>>(s0, s1, ds_idx[0], 5000);
  run_cheb<32, 32>(s1, s0, s2, s3, enc_w[1], enc_b[1], 5000, 0, RP(1), CS(1), CW(1), stream);
  k_ds<32><<<grid1((long)1250 * NB * 32), WG, 0, stream>>>(s0, s1, ds_idx[1], 1250);
  run_cheb<32, 64>(s1, s0, s2, s3, enc_w[2], enc_b[2], 1250, 0, RP(2), CS(2), CW(2), stream);
  k_ds<64><<<grid1((long)313 * NB * 64), WG, 0, stream>>>(s0, s1, ds_idx[2], 313);
  run_cheb<64, 64>(s1, s0, s2, s3, enc_w[3], enc_b[3], 313, 0, RP(3), CS(3), CW(3), stream);
  k_ds<64><<<grid1((long)79 * NB * 64), WG, 0, stream>>>(s0, s1, ds_idx[3], 79);

  // ---- latent ----
  k_latent<<<1024, 64, 0, stream>>>(s1, mu_w, mu_b, lv_w, lv_b, eps, label, mu_out, lv_out, hcat);
  k_declin<<<grid1(NB * 5056), WG, 0, stream>>>(hcat, dl_w, dl_b, s0);

  // ---- decoder ----
  k_us<64><<<grid1((long)313 * NB * 64), WG, 0, stream>>>(s0, s1, us_idx[3], us_w[3], 313);
  run_cheb<64, 64>(s1, s0, s2, s3, dec_w[0], dec_b[0], 313, 0, RP(3), CS(3), CW(3), stream);
  k_us<64><<<grid1((long)1250 * NB * 64), WG, 0, stream>>>(s0, s1, us_idx[2], us_w[2], 1250);
  run_cheb<64, 64>(s1, s0, s2, s3, dec_w[1], dec_b[1], 1250, 0, RP(2), CS(2), CW(2), stream);
  k_us<64><<<grid1((long)5000 * NB * 64), WG, 0, stream>>>(s0, s1, us_idx[1], us_w[1], 5000);
  run_cheb<64, 32>(s1, s0, s2, s3, dec_w[2], dec_b[2], 5000, 0, RP(1), CS(1), CW(1), stream);
  k_us<32><<<grid1((long)20000 * NB * 32), WG, 0, stream>>>(s0, s1, us_idx[0], us_w[0], 20000);
  run_cheb<32, 32>(s1, s0, s2, s3, dec_w[3], dec_b[3], 20000, 1, RP(0), CS(0), CW(0), stream);

  // ---- final level-4 cheb via shortcut + exact 79-node fixup ----
  k_final_short<<<grid1(NB * 20000), WG, 0, stream>>>(s0, dec_w[4], (float*)d_out);
  k_final_fix<<<16, 256, 0, stream>>>(s0, dec_w[4], RP(4), CS(4), CW(4), (float*)d_out);
}

// Round 6
// 1357.655 us; speedup vs baseline: 2.5786x; 2.5786x over previous
//
#include <hip/hip_runtime.h>
#include <cstdint>
#include <cstddef>

#define WG 256
#define NB 16  // batch

// Layout "L": arr[(n*16 + b)*F + f]  — node-major, batch, feature.
// A node's row is 16*F contiguous floats (2KB at F=32, 4KB at F=64).

// ---------------- small utility kernels ----------------

__global__ void k_zero_i(int* __restrict__ p, int n) {
  int i = blockIdx.x * WG + threadIdx.x;
  if (i < n) p[i] = 0;
}

__global__ void k_hist(const int* __restrict__ edges, int E,
                       int* __restrict__ dsrc, int* __restrict__ dtgt) {
  int e = blockIdx.x * WG + threadIdx.x;
  if (e >= E) return;
  atomicAdd(&dsrc[edges[e]], 1);
  atomicAdd(&dtgt[edges[E + e]], 1);
}

__global__ void k_scan(const int* __restrict__ deg, int N,
                       int* __restrict__ rowptr, int* __restrict__ cursor) {
  __shared__ int s[WG];
  int t = threadIdx.x;
  int chunk = (N + WG - 1) / WG;
  int a = t * chunk;
  int b = min(N, a + chunk);
  int sum = 0;
  for (int i = a; i < b; i++) sum += deg[i];
  s[t] = sum;
  __syncthreads();
  for (int off = 1; off < WG; off <<= 1) {
    int v = (t >= off) ? s[t - off] : 0;
    __syncthreads();
    s[t] += v;
    __syncthreads();
  }
  int run = (t == 0) ? 0 : s[t - 1];
  for (int i = a; i < b; i++) {
    rowptr[i] = run;
    cursor[i] = run;
    run += deg[i];
  }
  if (t == 0) rowptr[N] = s[WG - 1];
}

__global__ void k_fill(const int* __restrict__ edges, int E,
                       const int* __restrict__ dsrc, int* __restrict__ cursor,
                       int* __restrict__ csrc, float* __restrict__ csw) {
  int e = blockIdx.x * WG + threadIdx.x;
  if (e >= E) return;
  int s = edges[e], t = edges[E + e];
  float da = (float)dsrc[s], db = (float)dsrc[t];
  float wa = (da > 0.f) ? (1.0f / sqrtf(da)) : 0.f;
  float wb = (db > 0.f) ? (1.0f / sqrtf(db)) : 0.f;
  int pos = atomicAdd(&cursor[t], 1);
  csrc[pos] = s;
  csw[pos] = wa * wb;
}

// transpose x (b,n,f3) -> L layout (n,b,f3)
__global__ void k_tr_x(const float* __restrict__ x, float* __restrict__ out) {
  int i = blockIdx.x * WG + threadIdx.x;
  if (i >= NB * 20000 * 3) return;
  int f = i % 3;
  int b = (i / 3) % NB;
  int n = i / 48;
  out[i] = x[((size_t)b * 20000 + n) * 3 + f];
}

// ---------------- threefry eps (verified vs harness JAX ref) ----------------

static __device__ __forceinline__ float erfinv_f(float x) {
  float w = -log1pf(-x * x);
  float p;
  if (w < 5.0f) {
    w -= 2.5f;
    p = 2.81022636e-08f;
    p = fmaf(p, w, 3.43273939e-07f);
    p = fmaf(p, w, -3.5233877e-06f);
    p = fmaf(p, w, -4.39150654e-06f);
    p = fmaf(p, w, 0.00021858087f);
    p = fmaf(p, w, -0.00125372503f);
    p = fmaf(p, w, -0.00417768164f);
    p = fmaf(p, w, 0.246640727f);
    p = fmaf(p, w, 1.50140941f);
  } else {
    w = sqrtf(w) - 3.0f;
    p = -0.000200214257f;
    p = fmaf(p, w, 0.000100950558f);
    p = fmaf(p, w, 0.00134934322f);
    p = fmaf(p, w, -0.00367342844f);
    p = fmaf(p, w, 0.00573950773f);
    p = fmaf(p, w, -0.0076224613f);
    p = fmaf(p, w, 0.00943887047f);
    p = fmaf(p, w, 1.00167406f);
    p = fmaf(p, w, 2.83297682f);
  }
  return p * x;
}

static __device__ __forceinline__ float bits_to_normal(unsigned b) {
  float f = __uint_as_float((b >> 9) | 0x3f800000u) - 1.0f;
  const float lo = -0.99999994f;
  float u = f * (1.0f - lo) + lo;
  u = fmaxf(u, lo);
  return 1.41421356f * erfinv_f(u);
}

__global__ void k_eps(float* __restrict__ eps) {
  int i = blockIdx.x * WG + threadIdx.x;
  if (i >= 1024) return;
  unsigned x0 = 0u, x1 = (unsigned)i;
  unsigned ks[3] = {0u, 42u, 0u ^ 42u ^ 0x1BD11BDAu};
  x0 += ks[0];
  x1 += ks[1];
  const int R[2][4] = {{13, 15, 26, 6}, {17, 29, 16, 24}};
#pragma unroll
  for (int it = 0; it < 5; it++) {
#pragma unroll
    for (int j = 0; j < 4; j++) {
      x0 += x1;
      int r = R[it & 1][j];
      x1 = (x1 << r) | (x1 >> (32 - r));
      x1 ^= x0;
    }
    x0 += ks[(it + 1) % 3];
    x1 += ks[(it + 2) % 3] + (unsigned)(it + 1);
  }
  eps[i] = bits_to_normal(x0 ^ x1);
}

// ---------------- wave-per-node Chebyshev propagation ----------------

template <int F>
__global__ __launch_bounds__(WG) void k_propw(const float* __restrict__ in,
                                              float* __restrict__ out,
                                              const float* __restrict__ sub, float scale,
                                              const int* __restrict__ rowptr,
                                              const int* __restrict__ csrc,
                                              const float* __restrict__ csw, int N) {
  constexpr int C4 = F / 16;  // float4s per lane (2 for F=32, 4 for F=64)
  int node = blockIdx.x * 4 + (threadIdx.x >> 6);
  if (node >= N) return;
  int lane = threadIdx.x & 63;
  const float4* in4 = (const float4*)in;
  float4 acc[C4];
#pragma unroll
  for (int u = 0; u < C4; u++) acc[u] = make_float4(0.f, 0.f, 0.f, 0.f);
  int beg = rowptr[node], end = rowptr[node + 1];
  int j = beg;
  for (; j + 1 < end; j += 2) {
    int s0 = __builtin_amdgcn_readfirstlane(csrc[j]);
    int s1 = __builtin_amdgcn_readfirstlane(csrc[j + 1]);
    float w0 = __int_as_float(__builtin_amdgcn_readfirstlane(__float_as_int(csw[j])));
    float w1 = __int_as_float(__builtin_amdgcn_readfirstlane(__float_as_int(csw[j + 1])));
    const float4* r0 = in4 + (size_t)s0 * (4 * F) + lane;
    const float4* r1 = in4 + (size_t)s1 * (4 * F) + lane;
#pragma unroll
    for (int u = 0; u < C4; u++) {
      float4 v0 = r0[u * 64];
      float4 v1 = r1[u * 64];
      acc[u].x = fmaf(w0, v0.x, acc[u].x); acc[u].y = fmaf(w0, v0.y, acc[u].y);
      acc[u].z = fmaf(w0, v0.z, acc[u].z); acc[u].w = fmaf(w0, v0.w, acc[u].w);
      acc[u].x = fmaf(w1, v1.x, acc[u].x); acc[u].y = fmaf(w1, v1.y, acc[u].y);
      acc[u].z = fmaf(w1, v1.z, acc[u].z); acc[u].w = fmaf(w1, v1.w, acc[u].w);
    }
  }
  if (j < end) {
    int s0 = __builtin_amdgcn_readfirstlane(csrc[j]);
    float w0 = __int_as_float(__builtin_amdgcn_readfirstlane(__float_as_int(csw[j])));
    const float4* r0 = in4 + (size_t)s0 * (4 * F) + lane;
#pragma unroll
    for (int u = 0; u < C4; u++) {
      float4 v0 = r0[u * 64];
      acc[u].x = fmaf(w0, v0.x, acc[u].x); acc[u].y = fmaf(w0, v0.y, acc[u].y);
      acc[u].z = fmaf(w0, v0.z, acc[u].z); acc[u].w = fmaf(w0, v0.w, acc[u].w);
    }
  }
  float4* o4 = (float4*)out + (size_t)node * (4 * F) + lane;
  if (sub) {
    const float4* s4 = (const float4*)sub + (size_t)node * (4 * F) + lane;
#pragma unroll
    for (int u = 0; u < C4; u++) {
      float4 sv = s4[u * 64];
      float4 r;
      r.x = fmaf(scale, acc[u].x, -sv.x); r.y = fmaf(scale, acc[u].y, -sv.y);
      r.z = fmaf(scale, acc[u].z, -sv.z); r.w = fmaf(scale, acc[u].w, -sv.w);
      o4[u * 64] = r;
    }
  } else {
#pragma unroll
    for (int u = 0; u < C4; u++) {
      float4 r;
      r.x = scale * acc[u].x; r.y = scale * acc[u].y;
      r.z = scale * acc[u].z; r.w = scale * acc[u].w;
      o4[u * 64] = r;
    }
  }
}

// F=3 variant: row = 48 floats; lanes 0..47 each own one float.
__global__ __launch_bounds__(WG) void k_propw3(const float* __restrict__ in,
                                               float* __restrict__ out,
                                               const float* __restrict__ sub, float scale,
                                               const int* __restrict__ rowptr,
                                               const int* __restrict__ csrc,
                                               const float* __restrict__ csw, int N) {
  int node = blockIdx.x * 4 + (threadIdx.x >> 6);
  if (node >= N) return;
  int lane = threadIdx.x & 63;
  if (lane >= 48) return;
  float acc = 0.f;
  int beg = rowptr[node], end = rowptr[node + 1];
  for (int j = beg; j < end; j++) {
    int s = __builtin_amdgcn_readfirstlane(csrc[j]);
    float w = __int_as_float(__builtin_amdgcn_readfirstlane(__float_as_int(csw[j])));
    acc = fmaf(w, in[(size_t)s * 48 + lane], acc);
  }
  float r = scale * acc;
  if (sub) r -= sub[(size_t)node * 48 + lane];
  out[(size_t)node * 48 + lane] = r;
}

// ---------------- fused 3-term GEMM, tiled (1 row x 4 cols per thread) ----------------
// out(row, cg*4..cg*4+3) (+)= sum_{kk<3} txs[kk](row,:) @ W[kk]
// block = 256 threads = (1024/G) rows x (G/4) col-groups. W in LDS.
// VGPR footprint ~30 (acc float4 + xv float4 + addrs) -> no spills, high occupancy.
struct Ptr3 {
  const float* p[3];
};

template <int F, int G>
__global__ __launch_bounds__(WG) void k_gemm3(Ptr3 txs, const float* __restrict__ W,
                                              const float* __restrict__ bias,
                                              float* __restrict__ out, int rows,
                                              int accum, int relu) {
  constexpr int CG = G / 4;    // col-groups per row
  constexpr int RPB = WG / CG; // rows per block
  __shared__ float sW[3 * F * G];
  for (int i = threadIdx.x; i < 3 * F * G; i += WG) sW[i] = W[i];
  __syncthreads();
  int cg = threadIdx.x % CG;
  int r = threadIdx.x / CG;
  int row = blockIdx.x * RPB + r;
  if (row >= rows) return;
  float* o = out + (size_t)row * G + cg * 4;
  float4 a;
  if (accum) {
    a = *(const float4*)o;
  } else if (bias) {
    a = *(const float4*)(bias + cg * 4);
  } else {
    a = make_float4(0.f, 0.f, 0.f, 0.f);
  }
#pragma unroll
  for (int kk = 0; kk < 3; kk++) {
    const float* t = txs.p[kk] + (size_t)row * F;
    const float* w = sW + kk * F * G + cg * 4;
    if constexpr (F == 3) {
      float x0 = t[0], x1 = t[1], x2 = t[2];
      float4 w0 = *(const float4*)(w + 0 * G);
      float4 w1 = *(const float4*)(w + 1 * G);
      float4 w2 = *(const float4*)(w + 2 * G);
      a.x = fmaf(x0, w0.x, a.x); a.y = fmaf(x0, w0.y, a.y); a.z = fmaf(x0, w0.z, a.z); a.w = fmaf(x0, w0.w, a.w);
      a.x = fmaf(x1, w1.x, a.x); a.y = fmaf(x1, w1.y, a.y); a.z = fmaf(x1, w1.z, a.z); a.w = fmaf(x1, w1.w, a.w);
      a.x = fmaf(x2, w2.x, a.x); a.y = fmaf(x2, w2.y, a.y); a.z = fmaf(x2, w2.z, a.z); a.w = fmaf(x2, w2.w, a.w);
    } else {
#pragma unroll
      for (int f = 0; f < F; f += 4) {
        float4 xv = *(const float4*)(t + f);
        float4 w0 = *(const float4*)(w + (f + 0) * G);
        float4 w1 = *(const float4*)(w + (f + 1) * G);
        float4 w2 = *(const float4*)(w + (f + 2) * G);
        float4 w3 = *(const float4*)(w + (f + 3) * G);
        a.x = fmaf(xv.x, w0.x, a.x); a.y = fmaf(xv.x, w0.y, a.y); a.z = fmaf(xv.x, w0.z, a.z); a.w = fmaf(xv.x, w0.w, a.w);
        a.x = fmaf(xv.y, w1.x, a.x); a.y = fmaf(xv.y, w1.y, a.y); a.z = fmaf(xv.y, w1.z, a.z); a.w = fmaf(xv.y, w1.w, a.w);
        a.x = fmaf(xv.z, w2.x, a.x); a.y = fmaf(xv.z, w2.y, a.y); a.z = fmaf(xv.z, w2.z, a.z); a.w = fmaf(xv.z, w2.w, a.w);
        a.x = fmaf(xv.w, w3.x, a.x); a.y = fmaf(xv.w, w3.y, a.y); a.z = fmaf(xv.w, w3.z, a.z); a.w = fmaf(xv.w, w3.w, a.w);
      }
    }
  }
  if (relu) {
    a.x = fmaxf(a.x, 0.f); a.y = fmaxf(a.y, 0.f);
    a.z = fmaxf(a.z, 0.f); a.w = fmaxf(a.w, 0.f);
  }
  *(float4*)o = a;
}

// ---- final level-4 cheb shortcut (L layout in, (b,n,f) out) ----
__global__ __launch_bounds__(WG) void k_final_short(const float* __restrict__ in,
                                                    const float* __restrict__ W,  // 6x32x3
                                                    float* __restrict__ out) {
  __shared__ float sW[96];
  if (threadIdx.x < 96)
    sW[threadIdx.x] = W[threadIdx.x] - W[192 + threadIdx.x] + W[384 + threadIdx.x];
  __syncthreads();
  int tid = blockIdx.x * WG + threadIdx.x;
  if (tid >= NB * 20000) return;
  int b = tid / 20000, n = tid % 20000;
  const float* t = in + ((size_t)n * 16 + b) * 32;
  float a0 = 0.f, a1 = 0.f, a2 = 0.f;
#pragma unroll
  for (int f = 0; f < 32; f += 4) {
    float4 v = *(const float4*)(t + f);
    a0 = fmaf(v.x, sW[(f + 0) * 3 + 0], a0); a1 = fmaf(v.x, sW[(f + 0) * 3 + 1], a1); a2 = fmaf(v.x, sW[(f + 0) * 3 + 2], a2);
    a0 = fmaf(v.y, sW[(f + 1) * 3 + 0], a0); a1 = fmaf(v.y, sW[(f + 1) * 3 + 1], a1); a2 = fmaf(v.y, sW[(f + 1) * 3 + 2], a2);
    a0 = fmaf(v.z, sW[(f + 2) * 3 + 0], a0); a1 = fmaf(v.z, sW[(f + 2) * 3 + 1], a1); a2 = fmaf(v.z, sW[(f + 2) * 3 + 2], a2);
    a0 = fmaf(v.w, sW[(f + 3) * 3 + 0], a0); a1 = fmaf(v.w, sW[(f + 3) * 3 + 1], a1); a2 = fmaf(v.w, sW[(f + 3) * 3 + 2], a2);
  }
  float* o = out + (size_t)tid * 3;
  o[0] = a0; o[1] = a1; o[2] = a2;
}

// exact K=6 fixup for the 79 real nodes; in is L layout. one block per batch.
__global__ __launch_bounds__(256) void k_final_fix(const float* __restrict__ in,
                                                   const float* __restrict__ W,  // 6x32x3
                                                   const int* __restrict__ rowptr,
                                                   const int* __restrict__ csrc,
                                                   const float* __restrict__ csw,
                                                   float* __restrict__ out) {
  __shared__ float B0[79 * 32], B1[79 * 32], B2[79 * 32];
  __shared__ float sacc[79 * 3];
  __shared__ float sW[576];
  int b = blockIdx.x, t = threadIdx.x;
  for (int i = t; i < 576; i += 256) sW[i] = W[i];
  for (int i = t; i < 2528; i += 256) {
    int r = i >> 5, f = i & 31;
    B0[i] = in[((size_t)r * 16 + b) * 32 + f];
  }
  __syncthreads();
  for (int i = t; i < 237; i += 256) {
    int r = i / 3, g = i % 3;
    float a = 0.f;
    for (int f = 0; f < 32; f++) a = fmaf(B0[r * 32 + f], sW[f * 3 + g], a);
    sacc[i] = a;
  }
  for (int i = t; i < 2528; i += 256) {
    int r = i >> 5, f = i & 31;
    float a = 0.f;
    for (int j = rowptr[r]; j < rowptr[r + 1]; j++) a = fmaf(csw[j], B0[csrc[j] * 32 + f], a);
    B1[i] = a;
  }
  __syncthreads();
  for (int i = t; i < 237; i += 256) {
    int r = i / 3, g = i % 3;
    float a = sacc[i];
    for (int f = 0; f < 32; f++) a = fmaf(B1[r * 32 + f], sW[96 + f * 3 + g], a);
    sacc[i] = a;
  }
  for (int i = t; i < 2528; i += 256) {
    int r = i >> 5, f = i & 31;
    float a = 0.f;
    for (int j = rowptr[r]; j < rowptr[r + 1]; j++) a = fmaf(csw[j], B1[csrc[j] * 32 + f], a);
    B2[i] = 2.f * a - B0[i];
  }
  __syncthreads();
  for (int i = t; i < 237; i += 256) {
    int r = i / 3, g = i % 3;
    float a = sacc[i];
    for (int f = 0; f < 32; f++) a = fmaf(B2[r * 32 + f], sW[192 + f * 3 + g], a);
    sacc[i] = a;
  }
  __syncthreads();
  for (int i = t; i < 2528; i += 256) {
    int r = i >> 5, f = i & 31;
    float a = 0.f;
    for (int j = rowptr[r]; j < rowptr[r + 1]; j++) a = fmaf(csw[j], B2[csrc[j] * 32 + f], a);
    B0[i] = 2.f * a - B1[i];
  }
  __syncthreads();
  for (int i = t; i < 237; i += 256) {
    int r = i / 3, g = i % 3;
    float a = sacc[i];
    for (int f = 0; f < 32; f++) a = fmaf(B0[r * 32 + f], sW[288 + f * 3 + g], a);
    sacc[i] = a;
  }
  __syncthreads();
  for (int i = t; i < 2528; i += 256) {
    int r = i >> 5, f = i & 31;
    float a = 0.f;
    for (int j = rowptr[r]; j < rowptr[r + 1]; j++) a = fmaf(csw[j], B0[csrc[j] * 32 + f], a);
    B1[i] = 2.f * a - B2[i];
  }
  __syncthreads();
  for (int i = t; i < 237; i += 256) {
    int r = i / 3, g = i % 3;
    float a = sacc[i];
    for (int f = 0; f < 32; f++) a = fmaf(B1[r * 32 + f], sW[384 + f * 3 + g], a);
    sacc[i] = a;
  }
  __syncthreads();
  for (int i = t; i < 2528; i += 256) {
    int r = i >> 5, f = i & 31;
    float a = 0.f;
    for (int j = rowptr[r]; j < rowptr[r + 1]; j++) a = fmaf(csw[j], B1[csrc[j] * 32 + f], a);
    B2[i] = 2.f * a - B0[i];
  }
  __syncthreads();
  for (int i = t; i < 237; i += 256) {
    int r = i / 3, g = i % 3;
    float a = sacc[i];
    for (int f = 0; f < 32; f++) a = fmaf(B2[r * 32 + f], sW[480 + f * 3 + g], a);
    out[((size_t)b * 20000 + r) * 3 + g] = a;
  }
}

// downsample in L layout: out row j <- relu(in row idx[j])
template <int F>
__global__ __launch_bounds__(WG) void k_ds(const float* __restrict__ in,
                                           float* __restrict__ out,
                                           const int* __restrict__ idx, int Nout) {
  int i = blockIdx.x * WG + threadIdx.x;
  int total = Nout * NB * F;
  if (i >= total) return;
  int pos = i % (NB * F);
  int j = i / (NB * F);
  float v = in[(size_t)idx[j] * NB * F + pos];
  out[i] = fmaxf(v, 0.f);
}

// upsample in L layout (relu fused on input)
template <int F>
__global__ __launch_bounds__(WG) void k_us(const float* __restrict__ in,
                                           float* __restrict__ out,
                                           const int* __restrict__ uidx,
                                           const float* __restrict__ uw, int Nf) {
  int i = blockIdx.x * WG + threadIdx.x;
  int total = Nf * NB * F;
  if (i >= total) return;
  int pos = i % (NB * F);
  int r = i / (NB * F);
  float acc = 0.f;
#pragma unroll
  for (int k = 0; k < 3; k++) {
    float v = in[(size_t)uidx[r * 3 + k] * NB * F + pos];
    acc = fmaf(uw[r * 3 + k], fmaxf(v, 0.f), acc);
  }
  out[i] = acc;
}

// ---------------- latent kernels (L layout h: (79,16,64)) ----------------

__global__ __launch_bounds__(64) void k_latent(const float* __restrict__ h,
                                               const float* __restrict__ muW,
                                               const float* __restrict__ muB,
                                               const float* __restrict__ lvW,
                                               const float* __restrict__ lvB,
                                               const float* __restrict__ eps,
                                               const float* __restrict__ label,
                                               float* __restrict__ mu_out,
                                               float* __restrict__ lv_out,
                                               float* __restrict__ hcat) {
  int b = blockIdx.x / 64;
  int g = blockIdx.x % 64;
  int l = threadIdx.x;
  float am = 0.f, al = 0.f;
  for (int i = l; i < 5056; i += 64) {
    int n = i >> 6, f = i & 63;
    float hv = h[(size_t)(n * 16 + b) * 64 + f];
    am = fmaf(hv, muW[(size_t)i * 64 + g], am);
    al = fmaf(hv, lvW[(size_t)i * 64 + g], al);
  }
  for (int off = 32; off > 0; off >>= 1) {
    am += __shfl_down(am, off, 64);
    al += __shfl_down(al, off, 64);
  }
  if (l == 0) {
    am += muB[g];
    al += lvB[g];
    mu_out[b * 64 + g] = am;
    lv_out[b * 64 + g] = al;
    hcat[b * 66 + g] = fmaf(eps[b * 64 + g], expf(0.5f * al), am);
    if (g < 2) hcat[b * 66 + 64 + g] = label[b * 2 + g];
  }
}

// writes dec_lin output directly in L layout (79,16,64)
__global__ __launch_bounds__(WG) void k_declin(const float* __restrict__ hcat,
                                               const float* __restrict__ W,
                                               const float* __restrict__ bias,
                                               float* __restrict__ out) {
  int idx = blockIdx.x * WG + threadIdx.x;
  if (idx >= NB * 5056) return;
  int b = idx / 5056, j = idx % 5056;
  int n = j >> 6, f = j & 63;
  float acc = bias[j];
  const float* hc = hcat + b * 66;
#pragma unroll
  for (int i = 0; i < 66; i++) acc = fmaf(hc[i], W[(size_t)i * 5056 + j], acc);
  out[(size_t)(n * 16 + b) * 64 + f] = fmaxf(acc, 0.f);
}

// ---------------- host orchestration ----------------

static inline dim3 grid1(long n) { return dim3((unsigned)((n + WG - 1) / WG)); }

// Cheb layer, fused: 4 buffers (in is clobbered as T3 after first gemm3).
template <int F, int G>
static void run_cheb(float* in, float* out, float* A, float* B,
                     const float* W, const float* bias, int N, int relu_last,
                     const int* rowptr, const int* csrc, const float* csw,
                     hipStream_t st) {
  int rows = NB * N;
  constexpr int RPB = WG / (G / 4);
  dim3 gG((unsigned)((rows + RPB - 1) / RPB));
  dim3 gP((unsigned)((N + 3) / 4));
  if constexpr (F == 3) {
    k_propw3<<<gP, WG, 0, st>>>(in, A, nullptr, 1.f, rowptr, csrc, csw, N);
    k_propw3<<<gP, WG, 0, st>>>(A, B, in, 2.f, rowptr, csrc, csw, N);
    Ptr3 p1{{in, A, B}};
    k_gemm3<F, G><<<gG, WG, 0, st>>>(p1, W, bias, out, rows, 0, 0);
    k_propw3<<<gP, WG, 0, st>>>(B, in, A, 2.f, rowptr, csrc, csw, N);
    k_propw3<<<gP, WG, 0, st>>>(in, A, B, 2.f, rowptr, csrc, csw, N);
    k_propw3<<<gP, WG, 0, st>>>(A, B, in, 2.f, rowptr, csrc, csw, N);
    Ptr3 p2{{in, A, B}};
    k_gemm3<F, G><<<gG, WG, 0, st>>>(p2, W + 3 * F * G, nullptr, out, rows, 1, relu_last);
  } else {
    k_propw<F><<<gP, WG, 0, st>>>(in, A, nullptr, 1.f, rowptr, csrc, csw, N);
    k_propw<F><<<gP, WG, 0, st>>>(A, B, in, 2.f, rowptr, csrc, csw, N);
    Ptr3 p1{{in, A, B}};
    k_gemm3<F, G><<<gG, WG, 0, st>>>(p1, W, bias, out, rows, 0, 0);
    k_propw<F><<<gP, WG, 0, st>>>(B, in, A, 2.f, rowptr, csrc, csw, N);   // T3
    k_propw<F><<<gP, WG, 0, st>>>(in, A, B, 2.f, rowptr, csrc, csw, N);   // T4
    k_propw<F><<<gP, WG, 0, st>>>(A, B, in, 2.f, rowptr, csrc, csw, N);   // T5
    Ptr3 p2{{in, A, B}};
    k_gemm3<F, G><<<gG, WG, 0, st>>>(p2, W + 3 * F * G, nullptr, out, rows, 1, relu_last);
  }
}

extern "C" void kernel_launch(void* const* d_in, const int* in_sizes, int n_in,
                              void* d_out, int out_size, void* d_ws, size_t ws_size,
                              hipStream_t stream) {
  static const int NN[5] = {20000, 5000, 1250, 313, 79};
  static const int EE[5] = {120000, 30000, 7500, 1878, 474};
  static const int NCSR[5] = {20000, 5000, 1250, 313, 20000};

  const float* x = (const float*)d_in[0];
  const float* label = (const float*)d_in[1];
  const int* edges[5];
  for (int l = 0; l < 5; l++) edges[l] = (const int*)d_in[2 + l];
  const int* ds_idx[4];
  const int* us_idx[4];
  const float* us_w[4];
  for (int i = 0; i < 4; i++) {
    ds_idx[i] = (const int*)d_in[7 + 3 * i];
    us_idx[i] = (const int*)d_in[8 + 3 * i];
    us_w[i] = (const float*)d_in[9 + 3 * i];
  }
  const float* enc_w[4];
  const float* enc_b[4];
  for (int i = 0; i < 4; i++) {
    enc_w[i] = (const float*)d_in[19 + 2 * i];
    enc_b[i] = (const float*)d_in[20 + 2 * i];
  }
  const float* dec_w[5];
  for (int i = 0; i < 5; i++) dec_w[i] = (const float*)d_in[27 + i];
  const float* dec_b[4];
  for (int i = 0; i < 4; i++) dec_b[i] = (const float*)d_in[32 + i];
  const float* mu_w = (const float*)d_in[36];
  const float* mu_b = (const float*)d_in[37];
  const float* lv_w = (const float*)d_in[38];
  const float* lv_b = (const float*)d_in[39];
  const float* dl_w = (const float*)d_in[40];
  const float* dl_b = (const float*)d_in[41];

  float* wsf = (float*)d_ws;
  size_t off = 0;
  auto carve = [&](size_t n) -> float* {
    float* p = wsf + off;
    off += (n + 63) & ~(size_t)63;
    return p;
  };
  const size_t SLOT = 10240000;  // 16*20000*32 floats
  float* s0 = carve(SLOT);
  float* s1 = carve(SLOT);
  float* s2 = carve(SLOT);
  float* s3 = carve(SLOT);
  float* sxl = carve(960000);  // x in L layout (20000,16,3)
  int* deg_all = (int*)carve(26642 + 46563);
  int* deg_src_all = deg_all;
  int* deg_tgt_all = deg_all + 26642;
  int* rowptr_all = (int*)carve(46568);
  int* cursor_all = (int*)carve(46563);
  int* csrc_all = (int*)carve(159852);
  float* csw_all = carve(159852);
  float* eps = carve(1024);
  float* hcat = carve(1056);

  int NOFF[5], COFF[5], ROFF[5], EOFF[5];
  {
    int na = 0, ca = 0, ra = 0, ea = 0;
    for (int l = 0; l < 5; l++) {
      NOFF[l] = na; na += NN[l];
      COFF[l] = ca; ca += NCSR[l];
      ROFF[l] = ra; ra += NCSR[l] + 1;
      EOFF[l] = ea; ea += EE[l];
    }
  }

  // ---- norms + CSR build ----
  k_zero_i<<<grid1(26642 + 46563), WG, 0, stream>>>(deg_all, 26642 + 46563);
  for (int l = 0; l < 5; l++)
    k_hist<<<grid1(EE[l]), WG, 0, stream>>>(edges[l], EE[l], deg_src_all + NOFF[l],
                                            deg_tgt_all + COFF[l]);
  for (int l = 0; l < 5; l++)
    k_scan<<<1, WG, 0, stream>>>(deg_tgt_all + COFF[l], NCSR[l], rowptr_all + ROFF[l],
                                 cursor_all + COFF[l]);
  for (int l = 0; l < 5; l++)
    k_fill<<<grid1(EE[l]), WG, 0, stream>>>(edges[l], EE[l], deg_src_all + NOFF[l],
                                            cursor_all + COFF[l], csrc_all + EOFF[l],
                                            csw_all + EOFF[l]);
  k_eps<<<4, WG, 0, stream>>>(eps);
  k_tr_x<<<grid1(960000), WG, 0, stream>>>(x, sxl);

  auto RP = [&](int l) { return rowptr_all + ROFF[l]; };
  auto CS = [&](int l) { return csrc_all + EOFF[l]; };
  auto CW = [&](int l) { return csw_all + EOFF[l]; };

  float* mu_out = (float*)d_out + 960000;
  float* lv_out = (float*)d_out + 961024;

  // ---- encoder ----
  run_cheb<3, 32>(sxl, s0, s2, s3, enc_w[0], enc_b[0], 20000, 0, RP(0), CS(0), CW(0), stream);
  k_ds<32><<<grid1((long)5000 * NB * 32), WG, 0, stream>>>(s0, s1, ds_idx[0], 5000);
  run_cheb<32, 32>(s1, s0, s2, s3, enc_w[1], enc_b[1], 5000, 0, RP(1), CS(1), CW(1), stream);
  k_ds<32><<<grid1((long)1250 * NB * 32), WG, 0, stream>>>(s0, s1, ds_idx[1], 1250);
  run_cheb<32, 64>(s1, s0, s2, s3, enc_w[2], enc_b[2], 1250, 0, RP(2), CS(2), CW(2), stream);
  k_ds<64><<<grid1((long)313 * NB * 64), WG, 0, stream>>>(s0, s1, ds_idx[2], 313);
  run_cheb<64, 64>(s1, s0, s2, s3, enc_w[3], enc_b[3], 313, 0, RP(3), CS(3), CW(3), stream);
  k_ds<64><<<grid1((long)79 * NB * 64), WG, 0, stream>>>(s0, s1, ds_idx[3], 79);

  // ---- latent ----
  k_latent<<<1024, 64, 0, stream>>>(s1, mu_w, mu_b, lv_w, lv_b, eps, label, mu_out, lv_out, hcat);
  k_declin<<<grid1(NB * 5056), WG, 0, stream>>>(hcat, dl_w, dl_b, s0);

  // ---- decoder ----
  k_us<64><<<grid1((long)313 * NB * 64), WG, 0, stream>>>(s0, s1, us_idx[3], us_w[3], 313);
  run_cheb<64, 64>(s1, s0, s2, s3, dec_w[0], dec_b[0], 313, 0, RP(3), CS(3), CW(3), stream);
  k_us<64><<<grid1((long)1250 * NB * 64), WG, 0, stream>>>(s0, s1, us_idx[2], us_w[2], 1250);
  run_cheb<64, 64>(s1, s0, s2, s3, dec_w[1], dec_b[1], 1250, 0, RP(2), CS(2), CW(2), stream);
  k_us<64><<<grid1((long)5000 * NB * 64), WG, 0, stream>>>(s0, s1, us_idx[1], us_w[1], 5000);
  run_cheb<64, 32>(s1, s0, s2, s3, dec_w[2], dec_b[2], 5000, 0, RP(1), CS(1), CW(1), stream);
  k_us<32><<<grid1((long)20000 * NB * 32), WG, 0, stream>>>(s0, s1, us_idx[0], us_w[0], 20000);
  run_cheb<32, 32>(s1, s0, s2, s3, dec_w[3], dec_b[3], 20000, 1, RP(0), CS(0), CW(0), stream);

  // ---- final level-4 cheb via shortcut + exact 79-node fixup ----
  k_final_short<<<grid1(NB * 20000), WG, 0, stream>>>(s0, dec_w[4], (float*)d_out);
  k_final_fix<<<16, 256, 0, stream>>>(s0, dec_w[4], RP(4), CS(4), CW(4), (float*)d_out);
}

// Round 7
// 1324.746 us; speedup vs baseline: 2.6427x; 1.0248x over previous
//
#include <hip/hip_runtime.h>
#include <cstdint>
#include <cstddef>

#define WG 256
#define NB 16  // batch

// Layout "L": arr[(n*16 + b)*F + f]  — node-major, batch, feature.

// ---------------- small utility kernels ----------------

__global__ void k_zero_i(int* __restrict__ p, int n) {
  int i = blockIdx.x * WG + threadIdx.x;
  if (i < n) p[i] = 0;
}

__global__ void k_hist(const int* __restrict__ edges, int E,
                       int* __restrict__ dsrc, int* __restrict__ dtgt) {
  int e = blockIdx.x * WG + threadIdx.x;
  if (e >= E) return;
  atomicAdd(&dsrc[edges[e]], 1);
  atomicAdd(&dtgt[edges[E + e]], 1);
}

__global__ void k_scan(const int* __restrict__ deg, int N,
                       int* __restrict__ rowptr, int* __restrict__ cursor) {
  __shared__ int s[WG];
  int t = threadIdx.x;
  int chunk = (N + WG - 1) / WG;
  int a = t * chunk;
  int b = min(N, a + chunk);
  int sum = 0;
  for (int i = a; i < b; i++) sum += deg[i];
  s[t] = sum;
  __syncthreads();
  for (int off = 1; off < WG; off <<= 1) {
    int v = (t >= off) ? s[t - off] : 0;
    __syncthreads();
    s[t] += v;
    __syncthreads();
  }
  int run = (t == 0) ? 0 : s[t - 1];
  for (int i = a; i < b; i++) {
    rowptr[i] = run;
    cursor[i] = run;
    run += deg[i];
  }
  if (t == 0) rowptr[N] = s[WG - 1];
}

__global__ void k_fill(const int* __restrict__ edges, int E,
                       const int* __restrict__ dsrc, int* __restrict__ cursor,
                       int* __restrict__ csrc, float* __restrict__ csw) {
  int e = blockIdx.x * WG + threadIdx.x;
  if (e >= E) return;
  int s = edges[e], t = edges[E + e];
  float da = (float)dsrc[s], db = (float)dsrc[t];
  float wa = (da > 0.f) ? (1.0f / sqrtf(da)) : 0.f;
  float wb = (db > 0.f) ? (1.0f / sqrtf(db)) : 0.f;
  int pos = atomicAdd(&cursor[t], 1);
  csrc[pos] = s;
  csw[pos] = wa * wb;
}

// transpose x (b,n,f3) -> L layout (n,b,f3)
__global__ void k_tr_x(const float* __restrict__ x, float* __restrict__ out) {
  int i = blockIdx.x * WG + threadIdx.x;
  if (i >= NB * 20000 * 3) return;
  int f = i % 3;
  int b = (i / 3) % NB;
  int n = i / 48;
  out[i] = x[((size_t)b * 20000 + n) * 3 + f];
}

// ---------------- threefry eps (verified vs harness JAX ref) ----------------

static __device__ __forceinline__ float erfinv_f(float x) {
  float w = -log1pf(-x * x);
  float p;
  if (w < 5.0f) {
    w -= 2.5f;
    p = 2.81022636e-08f;
    p = fmaf(p, w, 3.43273939e-07f);
    p = fmaf(p, w, -3.5233877e-06f);
    p = fmaf(p, w, -4.39150654e-06f);
    p = fmaf(p, w, 0.00021858087f);
    p = fmaf(p, w, -0.00125372503f);
    p = fmaf(p, w, -0.00417768164f);
    p = fmaf(p, w, 0.246640727f);
    p = fmaf(p, w, 1.50140941f);
  } else {
    w = sqrtf(w) - 3.0f;
    p = -0.000200214257f;
    p = fmaf(p, w, 0.000100950558f);
    p = fmaf(p, w, 0.00134934322f);
    p = fmaf(p, w, -0.00367342844f);
    p = fmaf(p, w, 0.00573950773f);
    p = fmaf(p, w, -0.0076224613f);
    p = fmaf(p, w, 0.00943887047f);
    p = fmaf(p, w, 1.00167406f);
    p = fmaf(p, w, 2.83297682f);
  }
  return p * x;
}

static __device__ __forceinline__ float bits_to_normal(unsigned b) {
  float f = __uint_as_float((b >> 9) | 0x3f800000u) - 1.0f;
  const float lo = -0.99999994f;
  float u = f * (1.0f - lo) + lo;
  u = fmaxf(u, lo);
  return 1.41421356f * erfinv_f(u);
}

__global__ void k_eps(float* __restrict__ eps) {
  int i = blockIdx.x * WG + threadIdx.x;
  if (i >= 1024) return;
  unsigned x0 = 0u, x1 = (unsigned)i;
  unsigned ks[3] = {0u, 42u, 0u ^ 42u ^ 0x1BD11BDAu};
  x0 += ks[0];
  x1 += ks[1];
  const int R[2][4] = {{13, 15, 26, 6}, {17, 29, 16, 24}};
#pragma unroll
  for (int it = 0; it < 5; it++) {
#pragma unroll
    for (int j = 0; j < 4; j++) {
      x0 += x1;
      int r = R[it & 1][j];
      x1 = (x1 << r) | (x1 >> (32 - r));
      x1 ^= x0;
    }
    x0 += ks[(it + 1) % 3];
    x1 += ks[(it + 2) % 3] + (unsigned)(it + 1);
  }
  eps[i] = bits_to_normal(x0 ^ x1);
}

// ---------------- wave-per-node Chebyshev propagation ----------------

template <int F>
__global__ __launch_bounds__(WG) void k_propw(const float* __restrict__ in,
                                              float* __restrict__ out,
                                              const float* __restrict__ sub, float scale,
                                              const int* __restrict__ rowptr,
                                              const int* __restrict__ csrc,
                                              const float* __restrict__ csw, int N) {
  constexpr int C4 = F / 16;
  int node = blockIdx.x * 4 + (threadIdx.x >> 6);
  if (node >= N) return;
  int lane = threadIdx.x & 63;
  const float4* in4 = (const float4*)in;
  float4 acc[C4];
#pragma unroll
  for (int u = 0; u < C4; u++) acc[u] = make_float4(0.f, 0.f, 0.f, 0.f);
  int beg = rowptr[node], end = rowptr[node + 1];
  int j = beg;
  for (; j + 1 < end; j += 2) {
    int s0 = __builtin_amdgcn_readfirstlane(csrc[j]);
    int s1 = __builtin_amdgcn_readfirstlane(csrc[j + 1]);
    float w0 = __int_as_float(__builtin_amdgcn_readfirstlane(__float_as_int(csw[j])));
    float w1 = __int_as_float(__builtin_amdgcn_readfirstlane(__float_as_int(csw[j + 1])));
    const float4* r0 = in4 + (size_t)s0 * (4 * F) + lane;
    const float4* r1 = in4 + (size_t)s1 * (4 * F) + lane;
#pragma unroll
    for (int u = 0; u < C4; u++) {
      float4 v0 = r0[u * 64];
      float4 v1 = r1[u * 64];
      acc[u].x = fmaf(w0, v0.x, acc[u].x); acc[u].y = fmaf(w0, v0.y, acc[u].y);
      acc[u].z = fmaf(w0, v0.z, acc[u].z); acc[u].w = fmaf(w0, v0.w, acc[u].w);
      acc[u].x = fmaf(w1, v1.x, acc[u].x); acc[u].y = fmaf(w1, v1.y, acc[u].y);
      acc[u].z = fmaf(w1, v1.z, acc[u].z); acc[u].w = fmaf(w1, v1.w, acc[u].w);
    }
  }
  if (j < end) {
    int s0 = __builtin_amdgcn_readfirstlane(csrc[j]);
    float w0 = __int_as_float(__builtin_amdgcn_readfirstlane(__float_as_int(csw[j])));
    const float4* r0 = in4 + (size_t)s0 * (4 * F) + lane;
#pragma unroll
    for (int u = 0; u < C4; u++) {
      float4 v0 = r0[u * 64];
      acc[u].x = fmaf(w0, v0.x, acc[u].x); acc[u].y = fmaf(w0, v0.y, acc[u].y);
      acc[u].z = fmaf(w0, v0.z, acc[u].z); acc[u].w = fmaf(w0, v0.w, acc[u].w);
    }
  }
  float4* o4 = (float4*)out + (size_t)node * (4 * F) + lane;
  if (sub) {
    const float4* s4 = (const float4*)sub + (size_t)node * (4 * F) + lane;
#pragma unroll
    for (int u = 0; u < C4; u++) {
      float4 sv = s4[u * 64];
      float4 r;
      r.x = fmaf(scale, acc[u].x, -sv.x); r.y = fmaf(scale, acc[u].y, -sv.y);
      r.z = fmaf(scale, acc[u].z, -sv.z); r.w = fmaf(scale, acc[u].w, -sv.w);
      o4[u * 64] = r;
    }
  } else {
#pragma unroll
    for (int u = 0; u < C4; u++) {
      float4 r;
      r.x = scale * acc[u].x; r.y = scale * acc[u].y;
      r.z = scale * acc[u].z; r.w = scale * acc[u].w;
      o4[u * 64] = r;
    }
  }
}

// F=3 variant: row = 48 floats; lanes 0..47 each own one float.
__global__ __launch_bounds__(WG) void k_propw3(const float* __restrict__ in,
                                               float* __restrict__ out,
                                               const float* __restrict__ sub, float scale,
                                               const int* __restrict__ rowptr,
                                               const int* __restrict__ csrc,
                                               const float* __restrict__ csw, int N) {
  int node = blockIdx.x * 4 + (threadIdx.x >> 6);
  if (node >= N) return;
  int lane = threadIdx.x & 63;
  if (lane >= 48) return;
  float acc = 0.f;
  int beg = rowptr[node], end = rowptr[node + 1];
  for (int j = beg; j < end; j++) {
    int s = __builtin_amdgcn_readfirstlane(csrc[j]);
    float w = __int_as_float(__builtin_amdgcn_readfirstlane(__float_as_int(csw[j])));
    acc = fmaf(w, in[(size_t)s * 48 + lane], acc);
  }
  float r = scale * acc;
  if (sub) r -= sub[(size_t)node * 48 + lane];
  out[(size_t)node * 48 + lane] = r;
}

// ---------------- fused 3-term GEMM, R=4 rows x 4 cols per thread ----------------
// out(row, cg*4..+3) (+)= sum_{kk<3} txs[kk](srcrow,:) @ W[kk]
// idx != nullptr: ds-fusion — out row ro (node j=ro>>4, b=ro&15) reads input
// rows idx[j]*16+b .. +3 (4-row group never crosses a node boundary).
struct Ptr3 {
  const float* p[3];
};

template <int F, int G>
__global__ __launch_bounds__(WG) void k_gemm3(Ptr3 txs, const float* __restrict__ W,
                                              const float* __restrict__ bias,
                                              float* __restrict__ out, int rows,
                                              const int* __restrict__ idx,
                                              int accum, int relu) {
  constexpr int CG = G / 4;    // col-groups
  constexpr int RT = WG / CG;  // row-threads per block
  constexpr int RPB = RT * 4;  // rows per block
  __shared__ float sW[3 * F * G];
  for (int i = threadIdx.x; i < 3 * F * G; i += WG) sW[i] = W[i];
  __syncthreads();
  int cg = threadIdx.x % CG;
  int rt = threadIdx.x / CG;
  int row0 = blockIdx.x * RPB + rt * 4;
  if (row0 >= rows) return;  // rows % 4 == 0 always (16 rows per node)
  size_t src0;
  if (idx) {
    int node = row0 >> 4, b = row0 & 15;
    src0 = (size_t)idx[node] * 16 + b;
  } else {
    src0 = (size_t)row0;
  }
  float* o = out + (size_t)row0 * G + cg * 4;
  float4 acc[4];
  if (accum) {
#pragma unroll
    for (int r = 0; r < 4; r++) acc[r] = *(const float4*)(o + (size_t)r * G);
  } else if (bias) {
    float4 bv = *(const float4*)(bias + cg * 4);
#pragma unroll
    for (int r = 0; r < 4; r++) acc[r] = bv;
  } else {
#pragma unroll
    for (int r = 0; r < 4; r++) acc[r] = make_float4(0.f, 0.f, 0.f, 0.f);
  }
#pragma unroll
  for (int kk = 0; kk < 3; kk++) {
    const float* tb = txs.p[kk] + src0 * F;
    const float* w = sW + kk * F * G + cg * 4;
    if constexpr (F == 3) {
      float4 w0 = *(const float4*)(w + 0 * G);
      float4 w1 = *(const float4*)(w + 1 * G);
      float4 w2 = *(const float4*)(w + 2 * G);
#pragma unroll
      for (int r = 0; r < 4; r++) {
        float x0 = tb[r * 3 + 0], x1 = tb[r * 3 + 1], x2 = tb[r * 3 + 2];
        acc[r].x = fmaf(x0, w0.x, acc[r].x); acc[r].y = fmaf(x0, w0.y, acc[r].y);
        acc[r].z = fmaf(x0, w0.z, acc[r].z); acc[r].w = fmaf(x0, w0.w, acc[r].w);
        acc[r].x = fmaf(x1, w1.x, acc[r].x); acc[r].y = fmaf(x1, w1.y, acc[r].y);
        acc[r].z = fmaf(x1, w1.z, acc[r].z); acc[r].w = fmaf(x1, w1.w, acc[r].w);
        acc[r].x = fmaf(x2, w2.x, acc[r].x); acc[r].y = fmaf(x2, w2.y, acc[r].y);
        acc[r].z = fmaf(x2, w2.z, acc[r].z); acc[r].w = fmaf(x2, w2.w, acc[r].w);
      }
    } else {
#pragma unroll
      for (int fg = 0; fg < F / 4; fg++) {
        float4 w0 = *(const float4*)(w + (4 * fg + 0) * G);
        float4 w1 = *(const float4*)(w + (4 * fg + 1) * G);
        float4 w2 = *(const float4*)(w + (4 * fg + 2) * G);
        float4 w3 = *(const float4*)(w + (4 * fg + 3) * G);
#pragma unroll
        for (int r = 0; r < 4; r++) {
          float4 xv = *(const float4*)(tb + (size_t)r * F + 4 * fg);
          acc[r].x = fmaf(xv.x, w0.x, acc[r].x); acc[r].y = fmaf(xv.x, w0.y, acc[r].y);
          acc[r].z = fmaf(xv.x, w0.z, acc[r].z); acc[r].w = fmaf(xv.x, w0.w, acc[r].w);
          acc[r].x = fmaf(xv.y, w1.x, acc[r].x); acc[r].y = fmaf(xv.y, w1.y, acc[r].y);
          acc[r].z = fmaf(xv.y, w1.z, acc[r].z); acc[r].w = fmaf(xv.y, w1.w, acc[r].w);
          acc[r].x = fmaf(xv.z, w2.x, acc[r].x); acc[r].y = fmaf(xv.z, w2.y, acc[r].y);
          acc[r].z = fmaf(xv.z, w2.z, acc[r].z); acc[r].w = fmaf(xv.z, w2.w, acc[r].w);
          acc[r].x = fmaf(xv.w, w3.x, acc[r].x); acc[r].y = fmaf(xv.w, w3.y, acc[r].y);
          acc[r].z = fmaf(xv.w, w3.z, acc[r].z); acc[r].w = fmaf(xv.w, w3.w, acc[r].w);
        }
      }
    }
  }
  if (relu) {
#pragma unroll
    for (int r = 0; r < 4; r++) {
      acc[r].x = fmaxf(acc[r].x, 0.f); acc[r].y = fmaxf(acc[r].y, 0.f);
      acc[r].z = fmaxf(acc[r].z, 0.f); acc[r].w = fmaxf(acc[r].w, 0.f);
    }
  }
#pragma unroll
  for (int r = 0; r < 4; r++) *(float4*)(o + (size_t)r * G) = acc[r];
}

// ---- final level-4 cheb shortcut (L layout in, (b,n,f) out) ----
__global__ __launch_bounds__(WG) void k_final_short(const float* __restrict__ in,
                                                    const float* __restrict__ W,  // 6x32x3
                                                    float* __restrict__ out) {
  __shared__ float sW[96];
  if (threadIdx.x < 96)
    sW[threadIdx.x] = W[threadIdx.x] - W[192 + threadIdx.x] + W[384 + threadIdx.x];
  __syncthreads();
  int tid = blockIdx.x * WG + threadIdx.x;
  if (tid >= NB * 20000) return;
  int b = tid / 20000, n = tid % 20000;
  const float* t = in + ((size_t)n * 16 + b) * 32;
  float a0 = 0.f, a1 = 0.f, a2 = 0.f;
#pragma unroll
  for (int f = 0; f < 32; f += 4) {
    float4 v = *(const float4*)(t + f);
    a0 = fmaf(v.x, sW[(f + 0) * 3 + 0], a0); a1 = fmaf(v.x, sW[(f + 0) * 3 + 1], a1); a2 = fmaf(v.x, sW[(f + 0) * 3 + 2], a2);
    a0 = fmaf(v.y, sW[(f + 1) * 3 + 0], a0); a1 = fmaf(v.y, sW[(f + 1) * 3 + 1], a1); a2 = fmaf(v.y, sW[(f + 1) * 3 + 2], a2);
    a0 = fmaf(v.z, sW[(f + 2) * 3 + 0], a0); a1 = fmaf(v.z, sW[(f + 2) * 3 + 1], a1); a2 = fmaf(v.z, sW[(f + 2) * 3 + 2], a2);
    a0 = fmaf(v.w, sW[(f + 3) * 3 + 0], a0); a1 = fmaf(v.w, sW[(f + 3) * 3 + 1], a1); a2 = fmaf(v.w, sW[(f + 3) * 3 + 2], a2);
  }
  float* o = out + (size_t)tid * 3;
  o[0] = a0; o[1] = a1; o[2] = a2;
}

// exact K=6 fixup for the 79 real nodes; in is L layout. one block per batch.
__global__ __launch_bounds__(256) void k_final_fix(const float* __restrict__ in,
                                                   const float* __restrict__ W,  // 6x32x3
                                                   const int* __restrict__ rowptr,
                                                   const int* __restrict__ csrc,
                                                   const float* __restrict__ csw,
                                                   float* __restrict__ out) {
  __shared__ float B0[79 * 32], B1[79 * 32], B2[79 * 32];
  __shared__ float sacc[79 * 3];
  __shared__ float sW[576];
  int b = blockIdx.x, t = threadIdx.x;
  for (int i = t; i < 576; i += 256) sW[i] = W[i];
  for (int i = t; i < 2528; i += 256) {
    int r = i >> 5, f = i & 31;
    B0[i] = in[((size_t)r * 16 + b) * 32 + f];
  }
  __syncthreads();
  for (int i = t; i < 237; i += 256) {
    int r = i / 3, g = i % 3;
    float a = 0.f;
    for (int f = 0; f < 32; f++) a = fmaf(B0[r * 32 + f], sW[f * 3 + g], a);
    sacc[i] = a;
  }
  for (int i = t; i < 2528; i += 256) {
    int r = i >> 5, f = i & 31;
    float a = 0.f;
    for (int j = rowptr[r]; j < rowptr[r + 1]; j++) a = fmaf(csw[j], B0[csrc[j] * 32 + f], a);
    B1[i] = a;
  }
  __syncthreads();
  for (int i = t; i < 237; i += 256) {
    int r = i / 3, g = i % 3;
    float a = sacc[i];
    for (int f = 0; f < 32; f++) a = fmaf(B1[r * 32 + f], sW[96 + f * 3 + g], a);
    sacc[i] = a;
  }
  for (int i = t; i < 2528; i += 256) {
    int r = i >> 5, f = i & 31;
    float a = 0.f;
    for (int j = rowptr[r]; j < rowptr[r + 1]; j++) a = fmaf(csw[j], B1[csrc[j] * 32 + f], a);
    B2[i] = 2.f * a - B0[i];
  }
  __syncthreads();
  for (int i = t; i < 237; i += 256) {
    int r = i / 3, g = i % 3;
    float a = sacc[i];
    for (int f = 0; f < 32; f++) a = fmaf(B2[r * 32 + f], sW[192 + f * 3 + g], a);
    sacc[i] = a;
  }
  __syncthreads();
  for (int i = t; i < 2528; i += 256) {
    int r = i >> 5, f = i & 31;
    float a = 0.f;
    for (int j = rowptr[r]; j < rowptr[r + 1]; j++) a = fmaf(csw[j], B2[csrc[j] * 32 + f], a);
    B0[i] = 2.f * a - B1[i];
  }
  __syncthreads();
  for (int i = t; i < 237; i += 256) {
    int r = i / 3, g = i % 3;
    float a = sacc[i];
    for (int f = 0; f < 32; f++) a = fmaf(B0[r * 32 + f], sW[288 + f * 3 + g], a);
    sacc[i] = a;
  }
  __syncthreads();
  for (int i = t; i < 2528; i += 256) {
    int r = i >> 5, f = i & 31;
    float a = 0.f;
    for (int j = rowptr[r]; j < rowptr[r + 1]; j++) a = fmaf(csw[j], B0[csrc[j] * 32 + f], a);
    B1[i] = 2.f * a - B2[i];
  }
  __syncthreads();
  for (int i = t; i < 237; i += 256) {
    int r = i / 3, g = i % 3;
    float a = sacc[i];
    for (int f = 0; f < 32; f++) a = fmaf(B1[r * 32 + f], sW[384 + f * 3 + g], a);
    sacc[i] = a;
  }
  __syncthreads();
  for (int i = t; i < 2528; i += 256) {
    int r = i >> 5, f = i & 31;
    float a = 0.f;
    for (int j = rowptr[r]; j < rowptr[r + 1]; j++) a = fmaf(csw[j], B1[csrc[j] * 32 + f], a);
    B2[i] = 2.f * a - B0[i];
  }
  __syncthreads();
  for (int i = t; i < 237; i += 256) {
    int r = i / 3, g = i % 3;
    float a = sacc[i];
    for (int f = 0; f < 32; f++) a = fmaf(B2[r * 32 + f], sW[480 + f * 3 + g], a);
    out[((size_t)b * 20000 + r) * 3 + g] = a;
  }
}

// upsample in L layout (relu fused on input)
template <int F>
__global__ __launch_bounds__(WG) void k_us(const float* __restrict__ in,
                                           float* __restrict__ out,
                                           const int* __restrict__ uidx,
                                           const float* __restrict__ uw, int Nf) {
  int i = blockIdx.x * WG + threadIdx.x;
  int total = Nf * NB * F;
  if (i >= total) return;
  int pos = i % (NB * F);
  int r = i / (NB * F);
  float acc = 0.f;
#pragma unroll
  for (int k = 0; k < 3; k++) {
    float v = in[(size_t)uidx[r * 3 + k] * NB * F + pos];
    acc = fmaf(uw[r * 3 + k], fmaxf(v, 0.f), acc);
  }
  out[i] = acc;
}

// ---------------- latent kernels (L layout h: (79,16,64)) ----------------

__global__ __launch_bounds__(64) void k_latent(const float* __restrict__ h,
                                               const float* __restrict__ muW,
                                               const float* __restrict__ muB,
                                               const float* __restrict__ lvW,
                                               const float* __restrict__ lvB,
                                               const float* __restrict__ eps,
                                               const float* __restrict__ label,
                                               float* __restrict__ mu_out,
                                               float* __restrict__ lv_out,
                                               float* __restrict__ hcat) {
  int b = blockIdx.x / 64;
  int g = blockIdx.x % 64;
  int l = threadIdx.x;
  float am = 0.f, al = 0.f;
  for (int i = l; i < 5056; i += 64) {
    int n = i >> 6, f = i & 63;
    float hv = h[(size_t)(n * 16 + b) * 64 + f];
    am = fmaf(hv, muW[(size_t)i * 64 + g], am);
    al = fmaf(hv, lvW[(size_t)i * 64 + g], al);
  }
  for (int off = 32; off > 0; off >>= 1) {
    am += __shfl_down(am, off, 64);
    al += __shfl_down(al, off, 64);
  }
  if (l == 0) {
    am += muB[g];
    al += lvB[g];
    mu_out[b * 64 + g] = am;
    lv_out[b * 64 + g] = al;
    hcat[b * 66 + g] = fmaf(eps[b * 64 + g], expf(0.5f * al), am);
    if (g < 2) hcat[b * 66 + 64 + g] = label[b * 2 + g];
  }
}

// writes dec_lin output directly in L layout (79,16,64)
__global__ __launch_bounds__(WG) void k_declin(const float* __restrict__ hcat,
                                               const float* __restrict__ W,
                                               const float* __restrict__ bias,
                                               float* __restrict__ out) {
  int idx = blockIdx.x * WG + threadIdx.x;
  if (idx >= NB * 5056) return;
  int b = idx / 5056, j = idx % 5056;
  int n = j >> 6, f = j & 63;
  float acc = bias[j];
  const float* hc = hcat + b * 66;
#pragma unroll
  for (int i = 0; i < 66; i++) acc = fmaf(hc[i], W[(size_t)i * 5056 + j], acc);
  out[(size_t)(n * 16 + b) * 64 + f] = fmaxf(acc, 0.f);
}

// ---------------- host orchestration ----------------

static inline dim3 grid1(long n) { return dim3((unsigned)((n + WG - 1) / WG)); }

// Cheb layer: 5 props + 2 gemm3 passes (R=4 retile). If ds_idx != nullptr
// (encoder), both gemm passes compute only the Nout gathered nodes and pass 2
// applies relu (relu-then-gather == gather-then-relu).
template <int F, int G>
static void run_cheb(float* in, float* out, float* A, float* B,
                     const float* W, const float* bias, int N, int Nout,
                     const int* ds_idx, int relu_last,
                     const int* rowptr, const int* csrc, const float* csw,
                     hipStream_t st) {
  int orows = NB * Nout;
  constexpr int RPB = (WG / (G / 4)) * 4;
  dim3 gG((unsigned)((orows + RPB - 1) / RPB));
  dim3 gP((unsigned)((N + 3) / 4));
  int relu2 = ds_idx ? 1 : relu_last;
  if constexpr (F == 3) {
    k_propw3<<<gP, WG, 0, st>>>(in, A, nullptr, 1.f, rowptr, csrc, csw, N);
    k_propw3<<<gP, WG, 0, st>>>(A, B, in, 2.f, rowptr, csrc, csw, N);
    Ptr3 p1{{in, A, B}};
    k_gemm3<F, G><<<gG, WG, 0, st>>>(p1, W, bias, out, orows, ds_idx, 0, 0);
    k_propw3<<<gP, WG, 0, st>>>(B, in, A, 2.f, rowptr, csrc, csw, N);
    k_propw3<<<gP, WG, 0, st>>>(in, A, B, 2.f, rowptr, csrc, csw, N);
    k_propw3<<<gP, WG, 0, st>>>(A, B, in, 2.f, rowptr, csrc, csw, N);
    Ptr3 p2{{in, A, B}};
    k_gemm3<F, G><<<gG, WG, 0, st>>>(p2, W + 3 * F * G, nullptr, out, orows, ds_idx, 1, relu2);
  } else {
    k_propw<F><<<gP, WG, 0, st>>>(in, A, nullptr, 1.f, rowptr, csrc, csw, N);
    k_propw<F><<<gP, WG, 0, st>>>(A, B, in, 2.f, rowptr, csrc, csw, N);
    Ptr3 p1{{in, A, B}};
    k_gemm3<F, G><<<gG, WG, 0, st>>>(p1, W, bias, out, orows, ds_idx, 0, 0);
    k_propw<F><<<gP, WG, 0, st>>>(B, in, A, 2.f, rowptr, csrc, csw, N);   // T3
    k_propw<F><<<gP, WG, 0, st>>>(in, A, B, 2.f, rowptr, csrc, csw, N);   // T4
    k_propw<F><<<gP, WG, 0, st>>>(A, B, in, 2.f, rowptr, csrc, csw, N);   // T5
    Ptr3 p2{{in, A, B}};
    k_gemm3<F, G><<<gG, WG, 0, st>>>(p2, W + 3 * F * G, nullptr, out, orows, ds_idx, 1, relu2);
  }
}

extern "C" void kernel_launch(void* const* d_in, const int* in_sizes, int n_in,
                              void* d_out, int out_size, void* d_ws, size_t ws_size,
                              hipStream_t stream) {
  static const int NN[5] = {20000, 5000, 1250, 313, 79};
  static const int EE[5] = {120000, 30000, 7500, 1878, 474};
  static const int NCSR[5] = {20000, 5000, 1250, 313, 20000};

  const float* x = (const float*)d_in[0];
  const float* label = (const float*)d_in[1];
  const int* edges[5];
  for (int l = 0; l < 5; l++) edges[l] = (const int*)d_in[2 + l];
  const int* ds_idx[4];
  const int* us_idx[4];
  const float* us_w[4];
  for (int i = 0; i < 4; i++) {
    ds_idx[i] = (const int*)d_in[7 + 3 * i];
    us_idx[i] = (const int*)d_in[8 + 3 * i];
    us_w[i] = (const float*)d_in[9 + 3 * i];
  }
  const float* enc_w[4];
  const float* enc_b[4];
  for (int i = 0; i < 4; i++) {
    enc_w[i] = (const float*)d_in[19 + 2 * i];
    enc_b[i] = (const float*)d_in[20 + 2 * i];
  }
  const float* dec_w[5];
  for (int i = 0; i < 5; i++) dec_w[i] = (const float*)d_in[27 + i];
  const float* dec_b[4];
  for (int i = 0; i < 4; i++) dec_b[i] = (const float*)d_in[32 + i];
  const float* mu_w = (const float*)d_in[36];
  const float* mu_b = (const float*)d_in[37];
  const float* lv_w = (const float*)d_in[38];
  const float* lv_b = (const float*)d_in[39];
  const float* dl_w = (const float*)d_in[40];
  const float* dl_b = (const float*)d_in[41];

  float* wsf = (float*)d_ws;
  size_t off = 0;
  auto carve = [&](size_t n) -> float* {
    float* p = wsf + off;
    off += (n + 63) & ~(size_t)63;
    return p;
  };
  const size_t SLOT = 10240000;  // 16*20000*32 floats
  float* s0 = carve(SLOT);
  float* s1 = carve(SLOT);
  float* s2 = carve(SLOT);
  float* s3 = carve(SLOT);
  float* sxl = carve(960000);  // x in L layout (20000,16,3)
  int* deg_all = (int*)carve(26642 + 46563);
  int* deg_src_all = deg_all;
  int* deg_tgt_all = deg_all + 26642;
  int* rowptr_all = (int*)carve(46568);
  int* cursor_all = (int*)carve(46563);
  int* csrc_all = (int*)carve(159852);
  float* csw_all = carve(159852);
  float* eps = carve(1024);
  float* hcat = carve(1056);

  int NOFF[5], COFF[5], ROFF[5], EOFF[5];
  {
    int na = 0, ca = 0, ra = 0, ea = 0;
    for (int l = 0; l < 5; l++) {
      NOFF[l] = na; na += NN[l];
      COFF[l] = ca; ca += NCSR[l];
      ROFF[l] = ra; ra += NCSR[l] + 1;
      EOFF[l] = ea; ea += EE[l];
    }
  }

  // ---- norms + CSR build ----
  k_zero_i<<<grid1(26642 + 46563), WG, 0, stream>>>(deg_all, 26642 + 46563);
  for (int l = 0; l < 5; l++)
    k_hist<<<grid1(EE[l]), WG, 0, stream>>>(edges[l], EE[l], deg_src_all + NOFF[l],
                                            deg_tgt_all + COFF[l]);
  for (int l = 0; l < 5; l++)
    k_scan<<<1, WG, 0, stream>>>(deg_tgt_all + COFF[l], NCSR[l], rowptr_all + ROFF[l],
                                 cursor_all + COFF[l]);
  for (int l = 0; l < 5; l++)
    k_fill<<<grid1(EE[l]), WG, 0, stream>>>(edges[l], EE[l], deg_src_all + NOFF[l],
                                            cursor_all + COFF[l], csrc_all + EOFF[l],
                                            csw_all + EOFF[l]);
  k_eps<<<4, WG, 0, stream>>>(eps);
  k_tr_x<<<grid1(960000), WG, 0, stream>>>(x, sxl);

  auto RP = [&](int l) { return rowptr_all + ROFF[l]; };
  auto CS = [&](int l) { return csrc_all + EOFF[l]; };
  auto CW = [&](int l) { return csw_all + EOFF[l]; };

  float* mu_out = (float*)d_out + 960000;
  float* lv_out = (float*)d_out + 961024;

  // ---- encoder (ds+relu fused into gemm via row indirection) ----
  run_cheb<3, 32>(sxl, s1, s2, s3, enc_w[0], enc_b[0], 20000, 5000, ds_idx[0], 0,
                  RP(0), CS(0), CW(0), stream);
  run_cheb<32, 32>(s1, s0, s2, s3, enc_w[1], enc_b[1], 5000, 1250, ds_idx[1], 0,
                   RP(1), CS(1), CW(1), stream);
  run_cheb<32, 64>(s0, s1, s2, s3, enc_w[2], enc_b[2], 1250, 313, ds_idx[2], 0,
                   RP(2), CS(2), CW(2), stream);
  run_cheb<64, 64>(s1, s0, s2, s3, enc_w[3], enc_b[3], 313, 79, ds_idx[3], 0,
                   RP(3), CS(3), CW(3), stream);

  // ---- latent ----
  k_latent<<<1024, 64, 0, stream>>>(s0, mu_w, mu_b, lv_w, lv_b, eps, label, mu_out, lv_out, hcat);
  k_declin<<<grid1(NB * 5056), WG, 0, stream>>>(hcat, dl_w, dl_b, s0);

  // ---- decoder ----
  k_us<64><<<grid1((long)313 * NB * 64), WG, 0, stream>>>(s0, s1, us_idx[3], us_w[3], 313);
  run_cheb<64, 64>(s1, s0, s2, s3, dec_w[0], dec_b[0], 313, 313, nullptr, 0,
                   RP(3), CS(3), CW(3), stream);
  k_us<64><<<grid1((long)1250 * NB * 64), WG, 0, stream>>>(s0, s1, us_idx[2], us_w[2], 1250);
  run_cheb<64, 64>(s1, s0, s2, s3, dec_w[1], dec_b[1], 1250, 1250, nullptr, 0,
                   RP(2), CS(2), CW(2), stream);
  k_us<64><<<grid1((long)5000 * NB * 64), WG, 0, stream>>>(s0, s1, us_idx[1], us_w[1], 5000);
  run_cheb<64, 32>(s1, s0, s2, s3, dec_w[2], dec_b[2], 5000, 5000, nullptr, 0,
                   RP(1), CS(1), CW(1), stream);
  k_us<32><<<grid1((long)20000 * NB * 32), WG, 0, stream>>>(s0, s1, us_idx[0], us_w[0], 20000);
  run_cheb<32, 32>(s1, s0, s2, s3, dec_w[3], dec_b[3], 20000, 20000, nullptr, 1,
                   RP(0), CS(0), CW(0), stream);

  // ---- final level-4 cheb via shortcut + exact 79-node fixup ----
  k_final_short<<<grid1(NB * 20000), WG, 0, stream>>>(s0, dec_w[4], (float*)d_out);
  k_final_fix<<<16, 256, 0, stream>>>(s0, dec_w[4], RP(4), CS(4), CW(4), (float*)d_out);
}